// Round 7
// baseline (204.177 us; speedup 1.0000x reference)
//
#include <hip/hip_runtime.h>

#define BB 2
#define TT 2048
#define DD 1024
#define HH 16
#define HD 64
#define MM (BB*TT)

typedef __bf16 bf16;
typedef __bf16 bf16x4 __attribute__((ext_vector_type(4)));
typedef __bf16 bf16x8 __attribute__((ext_vector_type(8)));
typedef float  f32x4  __attribute__((ext_vector_type(4)));

#define QSCALE 0.1803368801111244f   // 0.125 * log2(e)
#define M0 16.0f                     // fixed softmax shift (exp2 domain)

__device__ __forceinline__ void gl_lds16(const void* g, void* l) {
  __builtin_amdgcn_global_load_lds(
      (const __attribute__((address_space(1))) void*)g,
      (__attribute__((address_space(3))) void*)l, 16, 0, 0);
}
__device__ __forceinline__ f32x4 mfma16(bf16x8 a, bf16x8 b, f32x4 c) {
  return __builtin_amdgcn_mfma_f32_16x16x32_bf16(a, b, c, 0, 0, 0);
}

// ---------------------------------------------------------------------------
// single fused convert: x (4M elems) + 4 weights (1M each) fp32 -> bf16
// ---------------------------------------------------------------------------
__global__ void cvt_all(const float* __restrict__ x,
                        const float* __restrict__ w0, const float* __restrict__ w1,
                        const float* __restrict__ w2, const float* __restrict__ w3,
                        bf16* __restrict__ xd,
                        bf16* __restrict__ d0, bf16* __restrict__ d1,
                        bf16* __restrict__ d2, bf16* __restrict__ d3) {
  int i = blockIdx.x * blockDim.x + threadIdx.x;   // 2M float4 slots
  const float* s;
  bf16* d;
  int off;
  if (i < (1 << 20)) { s = x; d = xd; off = i; }
  else {
    int j = (i - (1 << 20)) >> 18;
    off = (i - (1 << 20)) & ((1 << 18) - 1);
    s = (j == 0) ? w0 : (j == 1) ? w1 : (j == 2) ? w2 : w3;
    d = (j == 0) ? d0 : (j == 1) ? d1 : (j == 2) ? d2 : d3;
  }
  float4 v = ((const float4*)s)[off];
  bf16x4 o = { (bf16)v.x, (bf16)v.y, (bf16)v.z, (bf16)v.w };
  ((bf16x4*)d)[off] = o;
}

// ---------------------------------------------------------------------------
// Fused QKV — R6 (resubmit after container flake): same per-wave economics as
// R3 (BK=32, wave tile 32x64, 2x4 acc, 16 MFMA/step, proven swizzle,
// full-line epilogues — all verbatim) but decomposed into 256-thread blocks
// with 64x128 tiles: grid 1024 -> 4 blocks/CU (was 2), 4 independent barrier
// groups per CU at the same 16 waves/CU. K-axis edits (BK64/dbuf/restructure)
// all regressed (R2/R4/R5); this attacks drain-exposure via block overlap.
// Grid mapping keeps X-panel L2 locality: super-group G of 32 blocks
// (16 QK covering tokens [G*128,+128) x all dims; 16 V covering Wv x same
// tokens). LDS: QK 20KB, V 12KB.
// ---------------------------------------------------------------------------
__launch_bounds__(256)
__global__ void gemm_qkv(const bf16* __restrict__ X,
                         const bf16* __restrict__ Wq, const bf16* __restrict__ Wk,
                         const bf16* __restrict__ Wv,
                         const float* __restrict__ bq, const float* __restrict__ bk,
                         const float* __restrict__ bv,
                         bf16* __restrict__ qb, bf16* __restrict__ kb,
                         bf16* __restrict__ vtb,
                         float* __restrict__ kf, float* __restrict__ vf) {
  __shared__ bf16 sA[64 * 32];       // 4 KB
  __shared__ bf16 sB[2][128 * 32];   // 16 KB
  const int tid  = threadIdx.x;
  const int wv   = tid >> 6;                  // 0..3
  const int lane = tid & 63;
  const int quad = lane >> 4, l15 = lane & 15;
  const int wy   = wv >> 1, wx = wv & 1;      // wave grid 2x2 (32 rows x 64 cols)
  const int G    = blockIdx.x >> 5;           // 128-token super-group 0..31
  const int u    = blockIdx.x & 31;
  const int row  = tid >> 2;                  // 0..63
  const int c8   = ((tid & 3) ^ ((row >> 1) & 3)) * 8;  // swizzled source chunk
  const int rsw  = (l15 >> 1) & 3;            // read-side XOR
  const int ldst = wv * 1024;                 // per-wave byte offset

  if (u < 16) {
    // QK block: 64 tokens x 128 dims
    const int m0 = (2 * G + (u >> 3)) * 64;   // tokens
    const int n0 = (u & 7) * 128;             // output dim
    const bf16* Ab  = X  + (size_t)(m0 + row) * DD + c8;
    const bf16* Bqb = Wq + (size_t)(n0 + row) * DD + c8;
    const bf16* Bkb = Wk + (size_t)(n0 + row) * DD + c8;
    f32x4 accq[2][4] = {}, acck[2][4] = {};
    for (int k0 = 0; k0 < DD; k0 += 32) {
      gl_lds16(Ab  + k0,           (char*)sA    + ldst);
      gl_lds16(Bqb + k0,           (char*)sB[0] + ldst);
      gl_lds16(Bqb + 64 * DD + k0, (char*)sB[0] + 4096 + ldst);
      gl_lds16(Bkb + k0,           (char*)sB[1] + ldst);
      gl_lds16(Bkb + 64 * DD + k0, (char*)sB[1] + 4096 + ldst);
      __syncthreads();
      bf16x8 af[2], bq_[4], bk_[4];
#pragma unroll
      for (int mi = 0; mi < 2; mi++)
        af[mi] = *(const bf16x8*)(sA + (wy * 32 + mi * 16 + l15) * 32
                                     + ((quad ^ rsw) * 8));
#pragma unroll
      for (int ni = 0; ni < 4; ni++) {
        bq_[ni] = *(const bf16x8*)(sB[0] + (wx * 64 + ni * 16 + l15) * 32
                                         + ((quad ^ rsw) * 8));
        bk_[ni] = *(const bf16x8*)(sB[1] + (wx * 64 + ni * 16 + l15) * 32
                                         + ((quad ^ rsw) * 8));
      }
#pragma unroll
      for (int mi = 0; mi < 2; mi++)
#pragma unroll
        for (int ni = 0; ni < 4; ni++) {
          accq[mi][ni] = mfma16(af[mi], bq_[ni], accq[mi][ni]);
          acck[mi][ni] = mfma16(af[mi], bk_[ni], acck[mi][ni]);
        }
      __syncthreads();
    }
    for (int mi = 0; mi < 2; mi++)
      for (int ni = 0; ni < 4; ni++)
        for (int r = 0; r < 4; r++) {
          int m = m0 + wy * 32 + mi * 16 + quad * 4 + r;
          int n = n0 + wx * 64 + ni * 16 + l15;
          int b = m >> 11, t = m & (TT - 1);
          int h = n >> 6,  d = n & (HD - 1);
          size_t idx = ((size_t)(b * HH + h) * TT + t) * HD + d;
          qb[idx] = (bf16)((accq[mi][ni][r] + bq[n]) * QSCALE);
          float vk = acck[mi][ni][r] + bk[n];
          kb[idx] = (bf16)vk;
          kf[idx] = vk;
        }
  } else {
    // V block: 64 Wv rows x 128 tokens
    const int m0 = (u - 16) * 64;             // Wv rows (h*64+d)
    const int n0 = G * 128;                   // tokens
    const bf16* Ab = Wv + (size_t)(m0 + row) * DD + c8;
    const bf16* Bb = X  + (size_t)(n0 + row) * DD + c8;
    f32x4 acc[2][4] = {};
    for (int k0 = 0; k0 < DD; k0 += 32) {
      gl_lds16(Ab + k0,           (char*)sA    + ldst);
      gl_lds16(Bb + k0,           (char*)sB[0] + ldst);
      gl_lds16(Bb + 64 * DD + k0, (char*)sB[0] + 4096 + ldst);
      __syncthreads();
      bf16x8 af[2], bx_[4];
#pragma unroll
      for (int mi = 0; mi < 2; mi++)
        af[mi] = *(const bf16x8*)(sA + (wy * 32 + mi * 16 + l15) * 32
                                     + ((quad ^ rsw) * 8));
#pragma unroll
      for (int ni = 0; ni < 4; ni++)
        bx_[ni] = *(const bf16x8*)(sB[0] + (wx * 64 + ni * 16 + l15) * 32
                                        + ((quad ^ rsw) * 8));
#pragma unroll
      for (int mi = 0; mi < 2; mi++)
#pragma unroll
        for (int ni = 0; ni < 4; ni++)
          acc[mi][ni] = mfma16(af[mi], bx_[ni], acc[mi][ni]);
      __syncthreads();
    }
    for (int mi = 0; mi < 2; mi++) {
      int mbase = m0 + wy * 32 + mi * 16 + quad * 4;
      float brv[4];
      for (int r = 0; r < 4; r++) brv[r] = bv[mbase + r];
      int h = mbase >> 6, dbase = mbase & (HD - 1);
      for (int ni = 0; ni < 4; ni++) {
        int tok = n0 + wx * 64 + ni * 16 + l15;
        int b = tok >> 11, t = tok & (TT - 1);
        int bh = b * HH + h;
        float4 vv;
        float* vp = &vv.x;
        for (int r = 0; r < 4; r++) {
          float v = acc[mi][ni][r] + brv[r];
          vp[r] = v;
          vtb[((size_t)bh * HD + dbase + r) * TT + t] = (bf16)v;
        }
        *(float4*)&vf[((size_t)bh * TT + t) * HD + dbase] = vv;
      }
    }
  }
}

// ---------------------------------------------------------------------------
// gemm_o tile core (BK=64, swizzled) — R3 version (single-buffer, 2 barriers).
// ---------------------------------------------------------------------------
template<int BM, int BN>
__device__ __forceinline__ void tile_core64(const bf16* __restrict__ A,
                                            const bf16* __restrict__ W,
                                            int m0, int n0,
                                            bf16* sA, bf16* sB,
                                            f32x4 (&acc)[BM/32][BN/32]) {
  const int tid  = threadIdx.x;
  const int wv   = tid >> 6;
  const int l15  = tid & 15;
  const int quad = (tid & 63) >> 4;
  const int wy   = wv >> 1, wx = wv & 1;
  const int MI_  = BM / 32, NI_ = BN / 32;
  const int srow = tid >> 3;
  const int schk = (tid & 7) ^ (srow & 7);
  const int rswz = l15 & 7;
  const bf16* Ab = A + (size_t)(m0 + srow) * DD + schk * 8;
  const bf16* Wb = W + (size_t)(n0 + srow) * DD + schk * 8;
  char* lA = (char*)sA + wv * 1024;
  char* lB = (char*)sB + wv * 1024;
  for (int k0 = 0; k0 < DD; k0 += 64) {
#pragma unroll
    for (int j = 0; j < BM / 32; j++)
      gl_lds16(Ab + (size_t)j * 32 * DD + k0, lA + j * 4096);
#pragma unroll
    for (int j = 0; j < BN / 32; j++)
      gl_lds16(Wb + (size_t)j * 32 * DD + k0, lB + j * 4096);
    __syncthreads();
#pragma unroll
    for (int h = 0; h < 2; h++) {
      bf16x8 af[MI_], bw[NI_];
#pragma unroll
      for (int mi = 0; mi < MI_; mi++)
        af[mi] = *(const bf16x8*)(sA + (wy * (BM / 2) + mi * 16 + l15) * 64
                                     + (((h * 4 + quad) ^ rswz) * 8));
#pragma unroll
      for (int ni = 0; ni < NI_; ni++)
        bw[ni] = *(const bf16x8*)(sB + (wx * (BN / 2) + ni * 16 + l15) * 64
                                     + (((h * 4 + quad) ^ rswz) * 8));
#pragma unroll
      for (int mi = 0; mi < MI_; mi++)
#pragma unroll
        for (int ni = 0; ni < NI_; ni++)
          acc[mi][ni] = mfma16(af[mi], bw[ni], acc[mi][ni]);
    }
    __syncthreads();
  }
}

__launch_bounds__(256)
__global__ void gemm_o(const bf16* __restrict__ A, const bf16* __restrict__ W,
                       const float* __restrict__ bias, float* __restrict__ out) {
  __shared__ bf16 sA[64 * 64];
  __shared__ bf16 sB[128 * 64];
  const int m0 = blockIdx.x * 64;
  const int n0 = blockIdx.y * 128;
  f32x4 acc[2][4] = {};
  tile_core64<64, 128>(A, W, m0, n0, sA, sB, acc);
  const int wv = threadIdx.x >> 6;
  const int l15 = threadIdx.x & 15, quad = (threadIdx.x & 63) >> 4;
  const int wy = wv >> 1, wx = wv & 1;
  for (int mi = 0; mi < 2; mi++)
    for (int ni = 0; ni < 4; ni++)
      for (int r = 0; r < 4; r++) {
        int m = m0 + wy * 32 + mi * 16 + quad * 4 + r;
        int n = n0 + wx * 64 + ni * 16 + l15;
        out[(size_t)m * DD + n] = acc[mi][ni][r] + bias[n];
      }
}

// ---------------------------------------------------------------------------
// Flash attention (unchanged).
// ---------------------------------------------------------------------------
__launch_bounds__(256, 4)
__global__ void attn_fwd(const bf16* __restrict__ Q, const bf16* __restrict__ Kg,
                         const bf16* __restrict__ Vt, bf16* __restrict__ ctx) {
  __shared__ __align__(16) bf16 kbuf[2][4096];
  __shared__ __align__(16) bf16 vbuf[2][4096];
  __shared__ __align__(16) bf16 pbuf[4][1024];
  const int tid  = threadIdx.x;
  const int lane = tid & 63, wv = tid >> 6;
  const int quad = lane >> 4, l15 = lane & 15;
  const int bx = blockIdx.x;
  const int sl = bx >> 3;
  const int c  = 31 - (sl >> 2);
  const int bh = (bx & 7) + 8 * (sl & 3);
  const int qr = c * 64 + wv * 16;
  const int ntiles = c + 1;

  const bf16* Kbh = Kg + (size_t)bh * TT * HD;
  const bf16* Vbh = Vt + (size_t)bh * HD * TT;

  const int k0s = tid >> 3,  c0s = (tid & 7) ^ (k0s & 7);
  const int s1  = 256 + tid;
  const int k1s = s1 >> 3,   c1s = (s1 & 7) ^ (k1s & 7);

  int foff[4][2];
  for (int sub = 0; sub < 4; sub++)
    for (int h = 0; h < 2; h++)
      foff[sub][h] = (((sub * 16 + l15) * 8) + ((h * 4 + quad) ^ (l15 & 7))) * 8;

  const bf16* qp = Q + ((size_t)bh * TT + qr + l15) * HD + quad * 8;
  bf16x8 aq0 = *(const bf16x8*)qp;
  bf16x8 aq1 = *(const bf16x8*)(qp + 32);

  float lrow = 0.f;
  f32x4 acc[4] = {};
  bf16* pb = pbuf[wv];
  const int pswz = l15 & 7;

  gl_lds16(Kbh + (size_t)k0s * HD + c0s * 8, (char*)kbuf[0] + wv * 1024);
  gl_lds16(Kbh + (size_t)k1s * HD + c1s * 8, (char*)kbuf[0] + 4096 + wv * 1024);
  gl_lds16(Vbh + (size_t)k0s * TT + c0s * 8, (char*)vbuf[0] + wv * 1024);
  gl_lds16(Vbh + (size_t)k1s * TT + c1s * 8, (char*)vbuf[0] + 4096 + wv * 1024);

  for (int t = 0; t < ntiles; t++) {
    const int kt = t * 64;
    __syncthreads();
    if (t + 1 < ntiles) {
      bf16* kn = kbuf[(t + 1) & 1];
      bf16* vn = vbuf[(t + 1) & 1];
      gl_lds16(Kbh + (size_t)(kt + 64 + k0s) * HD + c0s * 8, (char*)kn + wv * 1024);
      gl_lds16(Kbh + (size_t)(kt + 64 + k1s) * HD + c1s * 8, (char*)kn + 4096 + wv * 1024);
      gl_lds16(Vbh + (size_t)k0s * TT + kt + 64 + c0s * 8, (char*)vn + wv * 1024);
      gl_lds16(Vbh + (size_t)k1s * TT + kt + 64 + c1s * 8, (char*)vn + 4096 + wv * 1024);
    }
    const bf16* kc = kbuf[t & 1];
    const bf16* vc = vbuf[t & 1];
    const bool last = (t == ntiles - 1);

    float p[4][4];
    for (int sub = 0; sub < 4; sub++) {
      if (last && kt + sub * 16 > qr + 15) {
        p[sub][0] = p[sub][1] = p[sub][2] = p[sub][3] = 0.f;
        continue;
      }
      bf16x8 ak0 = *(const bf16x8*)(kc + foff[sub][0]);
      bf16x8 ak1 = *(const bf16x8*)(kc + foff[sub][1]);
      f32x4 z = {};
      f32x4 st = mfma16(ak0, aq0, z);
      st = mfma16(ak1, aq1, st);
      if (last) {
        for (int r = 0; r < 4; r++) {
          int k_abs = kt + sub * 16 + quad * 4 + r;
          p[sub][r] = (k_abs > qr + l15) ? 0.f
                      : __builtin_amdgcn_exp2f(st[r] - M0);
        }
      } else {
        for (int r = 0; r < 4; r++)
          p[sub][r] = __builtin_amdgcn_exp2f(st[r] - M0);
      }
      lrow += (p[sub][0] + p[sub][1]) + (p[sub][2] + p[sub][3]);
    }

    for (int sub = 0; sub < 4; sub++) {
      bf16x4 pk = { (bf16)p[sub][0], (bf16)p[sub][1], (bf16)p[sub][2], (bf16)p[sub][3] };
      int cch = sub * 2 + (quad >> 1);
      *(bf16x4*)&pb[l15 * 64 + ((cch ^ pswz) * 8 + (quad & 1) * 4)] = pk;
    }
    bf16x8 ap0 = *(const bf16x8*)&pb[l15 * 64 + ((quad ^ pswz) * 8)];
    bf16x8 ap1 = *(const bf16x8*)&pb[l15 * 64 + (((4 + quad) ^ pswz) * 8)];

    for (int ni = 0; ni < 4; ni++) {
      bf16x8 v0 = *(const bf16x8*)(vc + foff[ni][0]);
      bf16x8 v1 = *(const bf16x8*)(vc + foff[ni][1]);
      acc[ni] = mfma16(ap0, v0, acc[ni]);
      acc[ni] = mfma16(ap1, v1, acc[ni]);
    }
  }

  lrow += __shfl_xor(lrow, 16, 64);
  lrow += __shfl_xor(lrow, 32, 64);
  float invl = 1.f / lrow;
  float invq[4];
  for (int r = 0; r < 4; r++)
    invq[r] = __shfl(invl, (lane & 48) | (quad * 4 + r), 64);
  int b = bh >> 4, h = bh & (HH - 1);
  for (int ni = 0; ni < 4; ni++)
    for (int r = 0; r < 4; r++) {
      int tq = qr + quad * 4 + r;
      ctx[((size_t)(b * TT + tq)) * DD + h * HD + ni * 16 + l15] = (bf16)(acc[ni][r] * invq[r]);
    }
}

// ---------------------------------------------------------------------------
// launch
// ---------------------------------------------------------------------------
extern "C" void kernel_launch(void* const* d_in, const int* in_sizes, int n_in,
                              void* d_out, int out_size, void* d_ws, size_t ws_size,
                              hipStream_t stream) {
  const float* x  = (const float*)d_in[0];
  const float* Wq = (const float*)d_in[1];
  const float* bq = (const float*)d_in[2];
  const float* Wk = (const float*)d_in[3];
  const float* bk = (const float*)d_in[4];
  const float* Wv = (const float*)d_in[5];
  const float* bv = (const float*)d_in[6];
  const float* Wo = (const float*)d_in[7];
  const float* bo = (const float*)d_in[8];
  float* out = (float*)d_out;
  float* outK = out + (size_t)MM * DD;
  float* outV = out + (size_t)2 * MM * DD;

  char* ws = (char*)d_ws;
  bf16* xb   = (bf16*)(ws);
  bf16* wqb  = (bf16*)(ws + (8  << 20));
  bf16* wkb  = (bf16*)(ws + (10 << 20));
  bf16* wvb  = (bf16*)(ws + (12 << 20));
  bf16* wob  = (bf16*)(ws + (14 << 20));
  bf16* qbuf = (bf16*)(ws + (16 << 20));
  bf16* kbuf = (bf16*)(ws + (24 << 20));
  bf16* vtb  = (bf16*)(ws + (32 << 20));
  bf16* ctxb = (bf16*)(ws + (40 << 20));

  cvt_all<<<(2 << 20) / 256, 256, 0, stream>>>(x, Wq, Wk, Wv, Wo,
                                               xb, wqb, wkb, wvb, wob);

  gemm_qkv<<<1024, 256, 0, stream>>>(xb, wqb, wkb, wvb, bq, bk, bv,
                                     qbuf, kbuf, vtb, outK, outV);

  attn_fwd<<<1024, 256, 0, stream>>>(qbuf, kbuf, vtb, ctxb);

  gemm_o<<<dim3(MM / 64, DD / 128), 256, 0, stream>>>(ctxb, wob, bo, out);
}

// Round 8
// 197.597 us; speedup vs baseline: 1.0333x; 1.0333x over previous
//
#include <hip/hip_runtime.h>

#define BB 2
#define TT 2048
#define DD 1024
#define HH 16
#define HD 64
#define MM (BB*TT)

typedef __bf16 bf16;
typedef __bf16 bf16x4 __attribute__((ext_vector_type(4)));
typedef __bf16 bf16x8 __attribute__((ext_vector_type(8)));
typedef float  f32x4  __attribute__((ext_vector_type(4)));

#define QSCALE 0.1803368801111244f   // 0.125 * log2(e)
#define M0 16.0f                     // fixed softmax shift (exp2 domain)

__device__ __forceinline__ void gl_lds16(const void* g, void* l) {
  __builtin_amdgcn_global_load_lds(
      (const __attribute__((address_space(1))) void*)g,
      (__attribute__((address_space(3))) void*)l, 16, 0, 0);
}
__device__ __forceinline__ f32x4 mfma16(bf16x8 a, bf16x8 b, f32x4 c) {
  return __builtin_amdgcn_mfma_f32_16x16x32_bf16(a, b, c, 0, 0, 0);
}

#define VMCNT3 asm volatile("s_waitcnt vmcnt(3)" ::: "memory")
#define VMCNT2 asm volatile("s_waitcnt vmcnt(2)" ::: "memory")
#define VMCNT0 asm volatile("s_waitcnt vmcnt(0)" ::: "memory")
#define BAR()  __builtin_amdgcn_s_barrier()
#define SBAR() __builtin_amdgcn_sched_barrier(0)

// ---------------------------------------------------------------------------
// single fused convert: x (4M elems) + 4 weights (1M each) fp32 -> bf16
// ---------------------------------------------------------------------------
__global__ void cvt_all(const float* __restrict__ x,
                        const float* __restrict__ w0, const float* __restrict__ w1,
                        const float* __restrict__ w2, const float* __restrict__ w3,
                        bf16* __restrict__ xd,
                        bf16* __restrict__ d0, bf16* __restrict__ d1,
                        bf16* __restrict__ d2, bf16* __restrict__ d3) {
  int i = blockIdx.x * blockDim.x + threadIdx.x;   // 2M float4 slots
  const float* s;
  bf16* d;
  int off;
  if (i < (1 << 20)) { s = x; d = xd; off = i; }
  else {
    int j = (i - (1 << 20)) >> 18;
    off = (i - (1 << 20)) & ((1 << 18) - 1);
    s = (j == 0) ? w0 : (j == 1) ? w1 : (j == 2) ? w2 : w3;
    d = (j == 0) ? d0 : (j == 1) ? d1 : (j == 2) ? d2 : d3;
  }
  float4 v = ((const float4*)s)[off];
  bf16x4 o = { (bf16)v.x, (bf16)v.y, (bf16)v.z, (bf16)v.w };
  ((bf16x4*)d)[off] = o;
}

// ---------------------------------------------------------------------------
// Fused QKV, 512 blocks x 512 threads (8 waves, wave grid 4x2) — R7.
// R3 decomposition verbatim (BK=32, 128x128 tiles, proven swizzle, full-line
// epilogues; R6's smaller blocks regressed via +60% staging redundancy).
// NEW: counted-vmcnt double-buffer (T3/T4 minimal port, m218/m248):
//   phase(buf b, step k): issue 3 gl_lds -> buf b^1 (step k+1);
//     vmcnt(3)  [own current-tile loads done; next-tile 3 stay in flight];
//     s_barrier; ds_read frags(buf b); MFMA; sched_barrier(0); s_barrier.
// K-loop unrolled x2 so buffer indices are compile-time literals (R4 lesson:
// runtime-alternating gl_lds dest serializes via M0). Tail pair peeled with
// vmcnt(0). Race audit: buf b^1 re-staged only after the post-compute barrier
// of the phase that last read it; sched_barrier(0) pins ds_read+MFMA before
// that barrier (rule #18). LDS 48KB -> 2 blocks/CU (same as R3).
// ---------------------------------------------------------------------------
__launch_bounds__(512)
__global__ void gemm_qkv(const bf16* __restrict__ X,
                         const bf16* __restrict__ Wq, const bf16* __restrict__ Wk,
                         const bf16* __restrict__ Wv,
                         const float* __restrict__ bq, const float* __restrict__ bk,
                         const float* __restrict__ bv,
                         bf16* __restrict__ qb, bf16* __restrict__ kb,
                         bf16* __restrict__ vtb,
                         float* __restrict__ kf, float* __restrict__ vf) {
  __shared__ bf16 sA[2][128 * 32];      // 16 KB
  __shared__ bf16 sB[2][2][128 * 32];   // 32 KB  [buf][q/k]
  const int tid  = threadIdx.x;
  const int wv   = tid >> 6;
  const int lane = tid & 63;
  const int quad = lane >> 4, l15 = lane & 15;
  const int wy   = wv >> 1, wx = wv & 1;      // wy 0..3, wx 0..1
  const int g    = blockIdx.x >> 4;
  const int j    = blockIdx.x & 15;
  const int row  = tid >> 2;                  // 0..127
  const int c8   = ((tid & 3) ^ ((row >> 1) & 3)) * 8;  // swizzled source chunk
  const int rsw  = (l15 >> 1) & 3;            // read-side XOR
  const int ldst = wv * 1024;                 // per-wave byte offset

  if (j < 8) {
    const int m0 = g * 128;                   // tokens
    const int n0 = j * 128;                   // output dim
    const bf16* Ab  = X  + (size_t)(m0 + row) * DD + c8;
    const bf16* Bqb = Wq + (size_t)(n0 + row) * DD + c8;
    const bf16* Bkb = Wk + (size_t)(n0 + row) * DD + c8;
    f32x4 accq[2][4] = {}, acck[2][4] = {};

#define STAGE_QK(B, K) \
    gl_lds16(Ab  + (K), (char*)sA[B]    + ldst); \
    gl_lds16(Bqb + (K), (char*)sB[B][0] + ldst); \
    gl_lds16(Bkb + (K), (char*)sB[B][1] + ldst);

#define COMP_QK(B) { \
    bf16x8 af[2], bq_[4], bk_[4]; \
    _Pragma("unroll") \
    for (int mi = 0; mi < 2; mi++) \
      af[mi] = *(const bf16x8*)(sA[B] + (wy * 32 + mi * 16 + l15) * 32 \
                                      + ((quad ^ rsw) * 8)); \
    _Pragma("unroll") \
    for (int ni = 0; ni < 4; ni++) { \
      bq_[ni] = *(const bf16x8*)(sB[B][0] + (wx * 64 + ni * 16 + l15) * 32 \
                                          + ((quad ^ rsw) * 8)); \
      bk_[ni] = *(const bf16x8*)(sB[B][1] + (wx * 64 + ni * 16 + l15) * 32 \
                                          + ((quad ^ rsw) * 8)); } \
    _Pragma("unroll") \
    for (int mi = 0; mi < 2; mi++) \
      _Pragma("unroll") \
      for (int ni = 0; ni < 4; ni++) { \
        accq[mi][ni] = mfma16(af[mi], bq_[ni], accq[mi][ni]); \
        acck[mi][ni] = mfma16(af[mi], bk_[ni], acck[mi][ni]); } }

    STAGE_QK(0, 0);
    for (int p = 0; p < 15; p++) {
      const int k = p * 64 + 32;
      STAGE_QK(1, k);              // next tile -> buf1
      VMCNT3; BAR();               // buf0 ready (3 newest stay in flight)
      COMP_QK(0);
      SBAR(); BAR();               // all reads of buf0 done before re-stage
      STAGE_QK(0, k + 32);
      VMCNT3; BAR();
      COMP_QK(1);
      SBAR(); BAR();
    }
    STAGE_QK(1, 992);
    VMCNT3; BAR();
    COMP_QK(0);                    // k = 960
    SBAR(); BAR();
    VMCNT0; BAR();
    COMP_QK(1);                    // k = 992

    for (int mi = 0; mi < 2; mi++)
      for (int ni = 0; ni < 4; ni++)
        for (int r = 0; r < 4; r++) {
          int m = m0 + wy * 32 + mi * 16 + quad * 4 + r;
          int n = n0 + wx * 64 + ni * 16 + l15;
          int b = m >> 11, t = m & (TT - 1);
          int h = n >> 6,  d = n & (HD - 1);
          size_t idx = ((size_t)(b * HH + h) * TT + t) * HD + d;
          qb[idx] = (bf16)((accq[mi][ni][r] + bq[n]) * QSCALE);
          float vk = acck[mi][ni][r] + bk[n];
          kb[idx] = (bf16)vk;
          kf[idx] = vk;
        }
  } else {
    const int m0 = (j - 8) * 128;             // Wv rows (h*64+d)
    const int n0 = g * 128;                   // tokens
    const bf16* Ab = Wv + (size_t)(m0 + row) * DD + c8;
    const bf16* Bb = X  + (size_t)(n0 + row) * DD + c8;
    f32x4 acc[2][4] = {};

#define STAGE_V(B, K) \
    gl_lds16(Ab + (K), (char*)sA[B]    + ldst); \
    gl_lds16(Bb + (K), (char*)sB[B][0] + ldst);

#define COMP_V(B) { \
    bf16x8 af[2], bx_[4]; \
    _Pragma("unroll") \
    for (int mi = 0; mi < 2; mi++) \
      af[mi] = *(const bf16x8*)(sA[B] + (wy * 32 + mi * 16 + l15) * 32 \
                                      + ((quad ^ rsw) * 8)); \
    _Pragma("unroll") \
    for (int ni = 0; ni < 4; ni++) \
      bx_[ni] = *(const bf16x8*)(sB[B][0] + (wx * 64 + ni * 16 + l15) * 32 \
                                          + ((quad ^ rsw) * 8)); \
    _Pragma("unroll") \
    for (int mi = 0; mi < 2; mi++) \
      _Pragma("unroll") \
      for (int ni = 0; ni < 4; ni++) \
        acc[mi][ni] = mfma16(af[mi], bx_[ni], acc[mi][ni]); }

    STAGE_V(0, 0);
    for (int p = 0; p < 15; p++) {
      const int k = p * 64 + 32;
      STAGE_V(1, k);
      VMCNT2; BAR();
      COMP_V(0);
      SBAR(); BAR();
      STAGE_V(0, k + 32);
      VMCNT2; BAR();
      COMP_V(1);
      SBAR(); BAR();
    }
    STAGE_V(1, 992);
    VMCNT2; BAR();
    COMP_V(0);
    SBAR(); BAR();
    VMCNT0; BAR();
    COMP_V(1);

    for (int mi = 0; mi < 2; mi++) {
      int mbase = m0 + wy * 32 + mi * 16 + quad * 4;
      float brv[4];
      for (int r = 0; r < 4; r++) brv[r] = bv[mbase + r];
      int h = mbase >> 6, dbase = mbase & (HD - 1);
      for (int ni = 0; ni < 4; ni++) {
        int tok = n0 + wx * 64 + ni * 16 + l15;
        int b = tok >> 11, t = tok & (TT - 1);
        int bh = b * HH + h;
        float4 vv;
        float* vp = &vv.x;
        for (int r = 0; r < 4; r++) {
          float v = acc[mi][ni][r] + brv[r];
          vp[r] = v;
          vtb[((size_t)bh * HD + dbase + r) * TT + t] = (bf16)v;
        }
        *(float4*)&vf[((size_t)bh * TT + t) * HD + dbase] = vv;
      }
    }
  }
}

// ---------------------------------------------------------------------------
// gemm_o tile core (BK=64, swizzled) — R3 version (single-buffer, 2 barriers).
// ---------------------------------------------------------------------------
template<int BM, int BN>
__device__ __forceinline__ void tile_core64(const bf16* __restrict__ A,
                                            const bf16* __restrict__ W,
                                            int m0, int n0,
                                            bf16* sA, bf16* sB,
                                            f32x4 (&acc)[BM/32][BN/32]) {
  const int tid  = threadIdx.x;
  const int wv   = tid >> 6;
  const int l15  = tid & 15;
  const int quad = (tid & 63) >> 4;
  const int wy   = wv >> 1, wx = wv & 1;
  const int MI_  = BM / 32, NI_ = BN / 32;
  const int srow = tid >> 3;
  const int schk = (tid & 7) ^ (srow & 7);
  const int rswz = l15 & 7;
  const bf16* Ab = A + (size_t)(m0 + srow) * DD + schk * 8;
  const bf16* Wb = W + (size_t)(n0 + srow) * DD + schk * 8;
  char* lA = (char*)sA + wv * 1024;
  char* lB = (char*)sB + wv * 1024;
  for (int k0 = 0; k0 < DD; k0 += 64) {
#pragma unroll
    for (int j = 0; j < BM / 32; j++)
      gl_lds16(Ab + (size_t)j * 32 * DD + k0, lA + j * 4096);
#pragma unroll
    for (int j = 0; j < BN / 32; j++)
      gl_lds16(Wb + (size_t)j * 32 * DD + k0, lB + j * 4096);
    __syncthreads();
#pragma unroll
    for (int h = 0; h < 2; h++) {
      bf16x8 af[MI_], bw[NI_];
#pragma unroll
      for (int mi = 0; mi < MI_; mi++)
        af[mi] = *(const bf16x8*)(sA + (wy * (BM / 2) + mi * 16 + l15) * 64
                                     + (((h * 4 + quad) ^ rswz) * 8));
#pragma unroll
      for (int ni = 0; ni < NI_; ni++)
        bw[ni] = *(const bf16x8*)(sB + (wx * (BN / 2) + ni * 16 + l15) * 64
                                     + (((h * 4 + quad) ^ rswz) * 8));
#pragma unroll
      for (int mi = 0; mi < MI_; mi++)
#pragma unroll
        for (int ni = 0; ni < NI_; ni++)
          acc[mi][ni] = mfma16(af[mi], bw[ni], acc[mi][ni]);
    }
    __syncthreads();
  }
}

__launch_bounds__(256)
__global__ void gemm_o(const bf16* __restrict__ A, const bf16* __restrict__ W,
                       const float* __restrict__ bias, float* __restrict__ out) {
  __shared__ bf16 sA[64 * 64];
  __shared__ bf16 sB[128 * 64];
  const int m0 = blockIdx.x * 64;
  const int n0 = blockIdx.y * 128;
  f32x4 acc[2][4] = {};
  tile_core64<64, 128>(A, W, m0, n0, sA, sB, acc);
  const int wv = threadIdx.x >> 6;
  const int l15 = threadIdx.x & 15, quad = (threadIdx.x & 63) >> 4;
  const int wy = wv >> 1, wx = wv & 1;
  for (int mi = 0; mi < 2; mi++)
    for (int ni = 0; ni < 4; ni++)
      for (int r = 0; r < 4; r++) {
        int m = m0 + wy * 32 + mi * 16 + quad * 4 + r;
        int n = n0 + wx * 64 + ni * 16 + l15;
        out[(size_t)m * DD + n] = acc[mi][ni][r] + bias[n];
      }
}

// ---------------------------------------------------------------------------
// Flash attention (unchanged).
// ---------------------------------------------------------------------------
__launch_bounds__(256, 4)
__global__ void attn_fwd(const bf16* __restrict__ Q, const bf16* __restrict__ Kg,
                         const bf16* __restrict__ Vt, bf16* __restrict__ ctx) {
  __shared__ __align__(16) bf16 kbuf[2][4096];
  __shared__ __align__(16) bf16 vbuf[2][4096];
  __shared__ __align__(16) bf16 pbuf[4][1024];
  const int tid  = threadIdx.x;
  const int lane = tid & 63, wv = tid >> 6;
  const int quad = lane >> 4, l15 = lane & 15;
  const int bx = blockIdx.x;
  const int sl = bx >> 3;
  const int c  = 31 - (sl >> 2);
  const int bh = (bx & 7) + 8 * (sl & 3);
  const int qr = c * 64 + wv * 16;
  const int ntiles = c + 1;

  const bf16* Kbh = Kg + (size_t)bh * TT * HD;
  const bf16* Vbh = Vt + (size_t)bh * HD * TT;

  const int k0s = tid >> 3,  c0s = (tid & 7) ^ (k0s & 7);
  const int s1  = 256 + tid;
  const int k1s = s1 >> 3,   c1s = (s1 & 7) ^ (k1s & 7);

  int foff[4][2];
  for (int sub = 0; sub < 4; sub++)
    for (int h = 0; h < 2; h++)
      foff[sub][h] = (((sub * 16 + l15) * 8) + ((h * 4 + quad) ^ (l15 & 7))) * 8;

  const bf16* qp = Q + ((size_t)bh * TT + qr + l15) * HD + quad * 8;
  bf16x8 aq0 = *(const bf16x8*)qp;
  bf16x8 aq1 = *(const bf16x8*)(qp + 32);

  float lrow = 0.f;
  f32x4 acc[4] = {};
  bf16* pb = pbuf[wv];
  const int pswz = l15 & 7;

  gl_lds16(Kbh + (size_t)k0s * HD + c0s * 8, (char*)kbuf[0] + wv * 1024);
  gl_lds16(Kbh + (size_t)k1s * HD + c1s * 8, (char*)kbuf[0] + 4096 + wv * 1024);
  gl_lds16(Vbh + (size_t)k0s * TT + c0s * 8, (char*)vbuf[0] + wv * 1024);
  gl_lds16(Vbh + (size_t)k1s * TT + c1s * 8, (char*)vbuf[0] + 4096 + wv * 1024);

  for (int t = 0; t < ntiles; t++) {
    const int kt = t * 64;
    __syncthreads();
    if (t + 1 < ntiles) {
      bf16* kn = kbuf[(t + 1) & 1];
      bf16* vn = vbuf[(t + 1) & 1];
      gl_lds16(Kbh + (size_t)(kt + 64 + k0s) * HD + c0s * 8, (char*)kn + wv * 1024);
      gl_lds16(Kbh + (size_t)(kt + 64 + k1s) * HD + c1s * 8, (char*)kn + 4096 + wv * 1024);
      gl_lds16(Vbh + (size_t)k0s * TT + kt + 64 + c0s * 8, (char*)vn + wv * 1024);
      gl_lds16(Vbh + (size_t)k1s * TT + kt + 64 + c1s * 8, (char*)vn + 4096 + wv * 1024);
    }
    const bf16* kc = kbuf[t & 1];
    const bf16* vc = vbuf[t & 1];
    const bool last = (t == ntiles - 1);

    float p[4][4];
    for (int sub = 0; sub < 4; sub++) {
      if (last && kt + sub * 16 > qr + 15) {
        p[sub][0] = p[sub][1] = p[sub][2] = p[sub][3] = 0.f;
        continue;
      }
      bf16x8 ak0 = *(const bf16x8*)(kc + foff[sub][0]);
      bf16x8 ak1 = *(const bf16x8*)(kc + foff[sub][1]);
      f32x4 z = {};
      f32x4 st = mfma16(ak0, aq0, z);
      st = mfma16(ak1, aq1, st);
      if (last) {
        for (int r = 0; r < 4; r++) {
          int k_abs = kt + sub * 16 + quad * 4 + r;
          p[sub][r] = (k_abs > qr + l15) ? 0.f
                      : __builtin_amdgcn_exp2f(st[r] - M0);
        }
      } else {
        for (int r = 0; r < 4; r++)
          p[sub][r] = __builtin_amdgcn_exp2f(st[r] - M0);
      }
      lrow += (p[sub][0] + p[sub][1]) + (p[sub][2] + p[sub][3]);
    }

    for (int sub = 0; sub < 4; sub++) {
      bf16x4 pk = { (bf16)p[sub][0], (bf16)p[sub][1], (bf16)p[sub][2], (bf16)p[sub][3] };
      int cch = sub * 2 + (quad >> 1);
      *(bf16x4*)&pb[l15 * 64 + ((cch ^ pswz) * 8 + (quad & 1) * 4)] = pk;
    }
    bf16x8 ap0 = *(const bf16x8*)&pb[l15 * 64 + ((quad ^ pswz) * 8)];
    bf16x8 ap1 = *(const bf16x8*)&pb[l15 * 64 + (((4 + quad) ^ pswz) * 8)];

    for (int ni = 0; ni < 4; ni++) {
      bf16x8 v0 = *(const bf16x8*)(vc + foff[ni][0]);
      bf16x8 v1 = *(const bf16x8*)(vc + foff[ni][1]);
      acc[ni] = mfma16(ap0, v0, acc[ni]);
      acc[ni] = mfma16(ap1, v1, acc[ni]);
    }
  }

  lrow += __shfl_xor(lrow, 16, 64);
  lrow += __shfl_xor(lrow, 32, 64);
  float invl = 1.f / lrow;
  float invq[4];
  for (int r = 0; r < 4; r++)
    invq[r] = __shfl(invl, (lane & 48) | (quad * 4 + r), 64);
  int b = bh >> 4, h = bh & (HH - 1);
  for (int ni = 0; ni < 4; ni++)
    for (int r = 0; r < 4; r++) {
      int tq = qr + quad * 4 + r;
      ctx[((size_t)(b * TT + tq)) * DD + h * HD + ni * 16 + l15] = (bf16)(acc[ni][r] * invq[r]);
    }
}

// ---------------------------------------------------------------------------
// launch
// ---------------------------------------------------------------------------
extern "C" void kernel_launch(void* const* d_in, const int* in_sizes, int n_in,
                              void* d_out, int out_size, void* d_ws, size_t ws_size,
                              hipStream_t stream) {
  const float* x  = (const float*)d_in[0];
  const float* Wq = (const float*)d_in[1];
  const float* bq = (const float*)d_in[2];
  const float* Wk = (const float*)d_in[3];
  const float* bk = (const float*)d_in[4];
  const float* Wv = (const float*)d_in[5];
  const float* bv = (const float*)d_in[6];
  const float* Wo = (const float*)d_in[7];
  const float* bo = (const float*)d_in[8];
  float* out = (float*)d_out;
  float* outK = out + (size_t)MM * DD;
  float* outV = out + (size_t)2 * MM * DD;

  char* ws = (char*)d_ws;
  bf16* xb   = (bf16*)(ws);
  bf16* wqb  = (bf16*)(ws + (8  << 20));
  bf16* wkb  = (bf16*)(ws + (10 << 20));
  bf16* wvb  = (bf16*)(ws + (12 << 20));
  bf16* wob  = (bf16*)(ws + (14 << 20));
  bf16* qbuf = (bf16*)(ws + (16 << 20));
  bf16* kbuf = (bf16*)(ws + (24 << 20));
  bf16* vtb  = (bf16*)(ws + (32 << 20));
  bf16* ctxb = (bf16*)(ws + (40 << 20));

  cvt_all<<<(2 << 20) / 256, 256, 0, stream>>>(x, Wq, Wk, Wv, Wo,
                                               xb, wqb, wkb, wvb, wob);

  gemm_qkv<<<512, 512, 0, stream>>>(xb, wqb, wkb, wvb, bq, bk, bv,
                                    qbuf, kbuf, vtb, outK, outV);

  attn_fwd<<<1024, 256, 0, stream>>>(qbuf, kbuf, vtb, ctxb);

  gemm_o<<<dim3(MM / 64, DD / 128), 256, 0, stream>>>(ctxb, wob, bo, out);
}

// Round 9
// 189.183 us; speedup vs baseline: 1.0793x; 1.0445x over previous
//
#include <hip/hip_runtime.h>

#define BB 2
#define TT 2048
#define DD 1024
#define HH 16
#define HD 64
#define MM (BB*TT)

typedef __bf16 bf16;
typedef __bf16 bf16x4 __attribute__((ext_vector_type(4)));
typedef __bf16 bf16x8 __attribute__((ext_vector_type(8)));
typedef float  f32x4  __attribute__((ext_vector_type(4)));

#define QSCALE 0.1803368801111244f   // 0.125 * log2(e)
#define M0 16.0f                     // fixed softmax shift (exp2 domain)

__device__ __forceinline__ void gl_lds16(const void* g, void* l) {
  __builtin_amdgcn_global_load_lds(
      (const __attribute__((address_space(1))) void*)g,
      (__attribute__((address_space(3))) void*)l, 16, 0, 0);
}
__device__ __forceinline__ f32x4 mfma16(bf16x8 a, bf16x8 b, f32x4 c) {
  return __builtin_amdgcn_mfma_f32_16x16x32_bf16(a, b, c, 0, 0, 0);
}

// ---------------------------------------------------------------------------
// single fused convert: x (4M elems) + 4 weights (1M each) fp32 -> bf16
// ---------------------------------------------------------------------------
__global__ void cvt_all(const float* __restrict__ x,
                        const float* __restrict__ w0, const float* __restrict__ w1,
                        const float* __restrict__ w2, const float* __restrict__ w3,
                        bf16* __restrict__ xd,
                        bf16* __restrict__ d0, bf16* __restrict__ d1,
                        bf16* __restrict__ d2, bf16* __restrict__ d3) {
  int i = blockIdx.x * blockDim.x + threadIdx.x;   // 2M float4 slots
  const float* s;
  bf16* d;
  int off;
  if (i < (1 << 20)) { s = x; d = xd; off = i; }
  else {
    int j = (i - (1 << 20)) >> 18;
    off = (i - (1 << 20)) & ((1 << 18) - 1);
    s = (j == 0) ? w0 : (j == 1) ? w1 : (j == 2) ? w2 : w3;
    d = (j == 0) ? d0 : (j == 1) ? d1 : (j == 2) ? d2 : d3;
  }
  float4 v = ((const float4*)s)[off];
  bf16x4 o = { (bf16)v.x, (bf16)v.y, (bf16)v.z, (bf16)v.w };
  ((bf16x4*)d)[off] = o;
}

// ---------------------------------------------------------------------------
// Fused QKV, 512 blocks x 512 threads (8 waves, wave grid 4x2) — R8.
// Base = R3 verbatim (BK=32, 2-barrier static-buffer loop, proven swizzle,
// full-line epilogues). Five structural K-loop edits (R2/R4/R5/R6/R7) all
// regressed; R3's compiler-scheduled 2-phase loop is the structure optimum.
// NEW (zero-cost): V-path K-loop starts at k=512 (wraps mod 1024). Dispatch
// arithmetic: co-resident pair per CU is (bid, bid+8) = QK(g) + V(g); both
// previously ran stage/drain/compute in lockstep so their vmcnt(0) drains
// overlapped instead of covering each other. Rotating V's K order
// anti-aligns the phases: one block's 16-MFMA phase now covers the other's
// drain. Same instructions, bytes, registers; only accumulation order
// changes (fp-benign).
// ---------------------------------------------------------------------------
__launch_bounds__(512)
__global__ void gemm_qkv(const bf16* __restrict__ X,
                         const bf16* __restrict__ Wq, const bf16* __restrict__ Wk,
                         const bf16* __restrict__ Wv,
                         const float* __restrict__ bq, const float* __restrict__ bk,
                         const float* __restrict__ bv,
                         bf16* __restrict__ qb, bf16* __restrict__ kb,
                         bf16* __restrict__ vtb,
                         float* __restrict__ kf, float* __restrict__ vf) {
  __shared__ bf16 sA[128 * 32];      // 8 KB
  __shared__ bf16 sB[2][128 * 32];   // 16 KB
  const int tid  = threadIdx.x;
  const int wv   = tid >> 6;
  const int lane = tid & 63;
  const int quad = lane >> 4, l15 = lane & 15;
  const int wy   = wv >> 1, wx = wv & 1;      // wy 0..3, wx 0..1
  const int g    = blockIdx.x >> 4;
  const int j    = blockIdx.x & 15;
  const int row  = tid >> 2;                  // 0..127
  const int c8   = ((tid & 3) ^ ((row >> 1) & 3)) * 8;  // swizzled source chunk
  const int rsw  = (l15 >> 1) & 3;            // read-side XOR
  char* lA  = (char*)sA    + wv * 1024;
  char* lB0 = (char*)sB[0] + wv * 1024;
  char* lB1 = (char*)sB[1] + wv * 1024;

  if (j < 8) {
    const int m0 = g * 128;                   // tokens
    const int n0 = j * 128;                   // output dim
    const bf16* Ab  = X  + (size_t)(m0 + row) * DD + c8;
    const bf16* Bqb = Wq + (size_t)(n0 + row) * DD + c8;
    const bf16* Bkb = Wk + (size_t)(n0 + row) * DD + c8;
    f32x4 accq[2][4] = {}, acck[2][4] = {};
    for (int k0 = 0; k0 < DD; k0 += 32) {
      gl_lds16(Ab  + k0, lA);
      gl_lds16(Bqb + k0, lB0);
      gl_lds16(Bkb + k0, lB1);
      __syncthreads();
      bf16x8 af[2], bq_[4], bk_[4];
#pragma unroll
      for (int mi = 0; mi < 2; mi++)
        af[mi] = *(const bf16x8*)(sA + (wy * 32 + mi * 16 + l15) * 32
                                     + ((quad ^ rsw) * 8));
#pragma unroll
      for (int ni = 0; ni < 4; ni++) {
        bq_[ni] = *(const bf16x8*)(sB[0] + (wx * 64 + ni * 16 + l15) * 32
                                         + ((quad ^ rsw) * 8));
        bk_[ni] = *(const bf16x8*)(sB[1] + (wx * 64 + ni * 16 + l15) * 32
                                         + ((quad ^ rsw) * 8));
      }
#pragma unroll
      for (int mi = 0; mi < 2; mi++)
#pragma unroll
        for (int ni = 0; ni < 4; ni++) {
          accq[mi][ni] = mfma16(af[mi], bq_[ni], accq[mi][ni]);
          acck[mi][ni] = mfma16(af[mi], bk_[ni], acck[mi][ni]);
        }
      __syncthreads();
    }
    for (int mi = 0; mi < 2; mi++)
      for (int ni = 0; ni < 4; ni++)
        for (int r = 0; r < 4; r++) {
          int m = m0 + wy * 32 + mi * 16 + quad * 4 + r;
          int n = n0 + wx * 64 + ni * 16 + l15;
          int b = m >> 11, t = m & (TT - 1);
          int h = n >> 6,  d = n & (HD - 1);
          size_t idx = ((size_t)(b * HH + h) * TT + t) * HD + d;
          qb[idx] = (bf16)((accq[mi][ni][r] + bq[n]) * QSCALE);
          float vk = acck[mi][ni][r] + bk[n];
          kb[idx] = (bf16)vk;
          kf[idx] = vk;
        }
  } else {
    const int m0 = (j - 8) * 128;             // Wv rows (h*64+d)
    const int n0 = g * 128;                   // tokens
    const bf16* Ab = Wv + (size_t)(m0 + row) * DD + c8;
    const bf16* Bb = X  + (size_t)(n0 + row) * DD + c8;
    f32x4 acc[2][4] = {};
    for (int i = 0; i < 32; i++) {
      const int k0 = ((i + 16) & 31) * 32;    // start at k=512, wrap (stagger)
      gl_lds16(Ab + k0, lA);
      gl_lds16(Bb + k0, lB0);
      __syncthreads();
      bf16x8 af[2], bx_[4];
#pragma unroll
      for (int mi = 0; mi < 2; mi++)
        af[mi] = *(const bf16x8*)(sA + (wy * 32 + mi * 16 + l15) * 32
                                     + ((quad ^ rsw) * 8));
#pragma unroll
      for (int ni = 0; ni < 4; ni++)
        bx_[ni] = *(const bf16x8*)(sB[0] + (wx * 64 + ni * 16 + l15) * 32
                                        + ((quad ^ rsw) * 8));
#pragma unroll
      for (int mi = 0; mi < 2; mi++)
#pragma unroll
        for (int ni = 0; ni < 4; ni++)
          acc[mi][ni] = mfma16(af[mi], bx_[ni], acc[mi][ni]);
      __syncthreads();
    }
    for (int mi = 0; mi < 2; mi++) {
      int mbase = m0 + wy * 32 + mi * 16 + quad * 4;
      float brv[4];
      for (int r = 0; r < 4; r++) brv[r] = bv[mbase + r];
      int h = mbase >> 6, dbase = mbase & (HD - 1);
      for (int ni = 0; ni < 4; ni++) {
        int tok = n0 + wx * 64 + ni * 16 + l15;
        int b = tok >> 11, t = tok & (TT - 1);
        int bh = b * HH + h;
        float4 vv;
        float* vp = &vv.x;
        for (int r = 0; r < 4; r++) {
          float v = acc[mi][ni][r] + brv[r];
          vp[r] = v;
          vtb[((size_t)bh * HD + dbase + r) * TT + t] = (bf16)v;
        }
        *(float4*)&vf[((size_t)bh * TT + t) * HD + dbase] = vv;
      }
    }
  }
}

// ---------------------------------------------------------------------------
// gemm_o tile core (BK=64, swizzled) — R3 version (single-buffer, 2 barriers).
// ---------------------------------------------------------------------------
template<int BM, int BN>
__device__ __forceinline__ void tile_core64(const bf16* __restrict__ A,
                                            const bf16* __restrict__ W,
                                            int m0, int n0,
                                            bf16* sA, bf16* sB,
                                            f32x4 (&acc)[BM/32][BN/32]) {
  const int tid  = threadIdx.x;
  const int wv   = tid >> 6;
  const int l15  = tid & 15;
  const int quad = (tid & 63) >> 4;
  const int wy   = wv >> 1, wx = wv & 1;
  const int MI_  = BM / 32, NI_ = BN / 32;
  const int srow = tid >> 3;
  const int schk = (tid & 7) ^ (srow & 7);
  const int rswz = l15 & 7;
  const bf16* Ab = A + (size_t)(m0 + srow) * DD + schk * 8;
  const bf16* Wb = W + (size_t)(n0 + srow) * DD + schk * 8;
  char* lA = (char*)sA + wv * 1024;
  char* lB = (char*)sB + wv * 1024;
  for (int k0 = 0; k0 < DD; k0 += 64) {
#pragma unroll
    for (int j = 0; j < BM / 32; j++)
      gl_lds16(Ab + (size_t)j * 32 * DD + k0, lA + j * 4096);
#pragma unroll
    for (int j = 0; j < BN / 32; j++)
      gl_lds16(Wb + (size_t)j * 32 * DD + k0, lB + j * 4096);
    __syncthreads();
#pragma unroll
    for (int h = 0; h < 2; h++) {
      bf16x8 af[MI_], bw[NI_];
#pragma unroll
      for (int mi = 0; mi < MI_; mi++)
        af[mi] = *(const bf16x8*)(sA + (wy * (BM / 2) + mi * 16 + l15) * 64
                                     + (((h * 4 + quad) ^ rswz) * 8));
#pragma unroll
      for (int ni = 0; ni < NI_; ni++)
        bw[ni] = *(const bf16x8*)(sB + (wx * (BN / 2) + ni * 16 + l15) * 64
                                     + (((h * 4 + quad) ^ rswz) * 8));
#pragma unroll
      for (int mi = 0; mi < MI_; mi++)
#pragma unroll
        for (int ni = 0; ni < NI_; ni++)
          acc[mi][ni] = mfma16(af[mi], bw[ni], acc[mi][ni]);
    }
    __syncthreads();
  }
}

__launch_bounds__(256)
__global__ void gemm_o(const bf16* __restrict__ A, const bf16* __restrict__ W,
                       const float* __restrict__ bias, float* __restrict__ out) {
  __shared__ bf16 sA[64 * 64];
  __shared__ bf16 sB[128 * 64];
  const int m0 = blockIdx.x * 64;
  const int n0 = blockIdx.y * 128;
  f32x4 acc[2][4] = {};
  tile_core64<64, 128>(A, W, m0, n0, sA, sB, acc);
  const int wv = threadIdx.x >> 6;
  const int l15 = threadIdx.x & 15, quad = (threadIdx.x & 63) >> 4;
  const int wy = wv >> 1, wx = wv & 1;
  for (int mi = 0; mi < 2; mi++)
    for (int ni = 0; ni < 4; ni++)
      for (int r = 0; r < 4; r++) {
        int m = m0 + wy * 32 + mi * 16 + quad * 4 + r;
        int n = n0 + wx * 64 + ni * 16 + l15;
        out[(size_t)m * DD + n] = acc[mi][ni][r] + bias[n];
      }
}

// ---------------------------------------------------------------------------
// Flash attention (unchanged).
// ---------------------------------------------------------------------------
__launch_bounds__(256, 4)
__global__ void attn_fwd(const bf16* __restrict__ Q, const bf16* __restrict__ Kg,
                         const bf16* __restrict__ Vt, bf16* __restrict__ ctx) {
  __shared__ __align__(16) bf16 kbuf[2][4096];
  __shared__ __align__(16) bf16 vbuf[2][4096];
  __shared__ __align__(16) bf16 pbuf[4][1024];
  const int tid  = threadIdx.x;
  const int lane = tid & 63, wv = tid >> 6;
  const int quad = lane >> 4, l15 = lane & 15;
  const int bx = blockIdx.x;
  const int sl = bx >> 3;
  const int c  = 31 - (sl >> 2);
  const int bh = (bx & 7) + 8 * (sl & 3);
  const int qr = c * 64 + wv * 16;
  const int ntiles = c + 1;

  const bf16* Kbh = Kg + (size_t)bh * TT * HD;
  const bf16* Vbh = Vt + (size_t)bh * HD * TT;

  const int k0s = tid >> 3,  c0s = (tid & 7) ^ (k0s & 7);
  const int s1  = 256 + tid;
  const int k1s = s1 >> 3,   c1s = (s1 & 7) ^ (k1s & 7);

  int foff[4][2];
  for (int sub = 0; sub < 4; sub++)
    for (int h = 0; h < 2; h++)
      foff[sub][h] = (((sub * 16 + l15) * 8) + ((h * 4 + quad) ^ (l15 & 7))) * 8;

  const bf16* qp = Q + ((size_t)bh * TT + qr + l15) * HD + quad * 8;
  bf16x8 aq0 = *(const bf16x8*)qp;
  bf16x8 aq1 = *(const bf16x8*)(qp + 32);

  float lrow = 0.f;
  f32x4 acc[4] = {};
  bf16* pb = pbuf[wv];
  const int pswz = l15 & 7;

  gl_lds16(Kbh + (size_t)k0s * HD + c0s * 8, (char*)kbuf[0] + wv * 1024);
  gl_lds16(Kbh + (size_t)k1s * HD + c1s * 8, (char*)kbuf[0] + 4096 + wv * 1024);
  gl_lds16(Vbh + (size_t)k0s * TT + c0s * 8, (char*)vbuf[0] + wv * 1024);
  gl_lds16(Vbh + (size_t)k1s * TT + c1s * 8, (char*)vbuf[0] + 4096 + wv * 1024);

  for (int t = 0; t < ntiles; t++) {
    const int kt = t * 64;
    __syncthreads();
    if (t + 1 < ntiles) {
      bf16* kn = kbuf[(t + 1) & 1];
      bf16* vn = vbuf[(t + 1) & 1];
      gl_lds16(Kbh + (size_t)(kt + 64 + k0s) * HD + c0s * 8, (char*)kn + wv * 1024);
      gl_lds16(Kbh + (size_t)(kt + 64 + k1s) * HD + c1s * 8, (char*)kn + 4096 + wv * 1024);
      gl_lds16(Vbh + (size_t)k0s * TT + kt + 64 + c0s * 8, (char*)vn + wv * 1024);
      gl_lds16(Vbh + (size_t)k1s * TT + kt + 64 + c1s * 8, (char*)vn + 4096 + wv * 1024);
    }
    const bf16* kc = kbuf[t & 1];
    const bf16* vc = vbuf[t & 1];
    const bool last = (t == ntiles - 1);

    float p[4][4];
    for (int sub = 0; sub < 4; sub++) {
      if (last && kt + sub * 16 > qr + 15) {
        p[sub][0] = p[sub][1] = p[sub][2] = p[sub][3] = 0.f;
        continue;
      }
      bf16x8 ak0 = *(const bf16x8*)(kc + foff[sub][0]);
      bf16x8 ak1 = *(const bf16x8*)(kc + foff[sub][1]);
      f32x4 z = {};
      f32x4 st = mfma16(ak0, aq0, z);
      st = mfma16(ak1, aq1, st);
      if (last) {
        for (int r = 0; r < 4; r++) {
          int k_abs = kt + sub * 16 + quad * 4 + r;
          p[sub][r] = (k_abs > qr + l15) ? 0.f
                      : __builtin_amdgcn_exp2f(st[r] - M0);
        }
      } else {
        for (int r = 0; r < 4; r++)
          p[sub][r] = __builtin_amdgcn_exp2f(st[r] - M0);
      }
      lrow += (p[sub][0] + p[sub][1]) + (p[sub][2] + p[sub][3]);
    }

    for (int sub = 0; sub < 4; sub++) {
      bf16x4 pk = { (bf16)p[sub][0], (bf16)p[sub][1], (bf16)p[sub][2], (bf16)p[sub][3] };
      int cch = sub * 2 + (quad >> 1);
      *(bf16x4*)&pb[l15 * 64 + ((cch ^ pswz) * 8 + (quad & 1) * 4)] = pk;
    }
    bf16x8 ap0 = *(const bf16x8*)&pb[l15 * 64 + ((quad ^ pswz) * 8)];
    bf16x8 ap1 = *(const bf16x8*)&pb[l15 * 64 + (((4 + quad) ^ pswz) * 8)];

    for (int ni = 0; ni < 4; ni++) {
      bf16x8 v0 = *(const bf16x8*)(vc + foff[ni][0]);
      bf16x8 v1 = *(const bf16x8*)(vc + foff[ni][1]);
      acc[ni] = mfma16(ap0, v0, acc[ni]);
      acc[ni] = mfma16(ap1, v1, acc[ni]);
    }
  }

  lrow += __shfl_xor(lrow, 16, 64);
  lrow += __shfl_xor(lrow, 32, 64);
  float invl = 1.f / lrow;
  float invq[4];
  for (int r = 0; r < 4; r++)
    invq[r] = __shfl(invl, (lane & 48) | (quad * 4 + r), 64);
  int b = bh >> 4, h = bh & (HH - 1);
  for (int ni = 0; ni < 4; ni++)
    for (int r = 0; r < 4; r++) {
      int tq = qr + quad * 4 + r;
      ctx[((size_t)(b * TT + tq)) * DD + h * HD + ni * 16 + l15] = (bf16)(acc[ni][r] * invq[r]);
    }
}

// ---------------------------------------------------------------------------
// launch
// ---------------------------------------------------------------------------
extern "C" void kernel_launch(void* const* d_in, const int* in_sizes, int n_in,
                              void* d_out, int out_size, void* d_ws, size_t ws_size,
                              hipStream_t stream) {
  const float* x  = (const float*)d_in[0];
  const float* Wq = (const float*)d_in[1];
  const float* bq = (const float*)d_in[2];
  const float* Wk = (const float*)d_in[3];
  const float* bk = (const float*)d_in[4];
  const float* Wv = (const float*)d_in[5];
  const float* bv = (const float*)d_in[6];
  const float* Wo = (const float*)d_in[7];
  const float* bo = (const float*)d_in[8];
  float* out = (float*)d_out;
  float* outK = out + (size_t)MM * DD;
  float* outV = out + (size_t)2 * MM * DD;

  char* ws = (char*)d_ws;
  bf16* xb   = (bf16*)(ws);
  bf16* wqb  = (bf16*)(ws + (8  << 20));
  bf16* wkb  = (bf16*)(ws + (10 << 20));
  bf16* wvb  = (bf16*)(ws + (12 << 20));
  bf16* wob  = (bf16*)(ws + (14 << 20));
  bf16* qbuf = (bf16*)(ws + (16 << 20));
  bf16* kbuf = (bf16*)(ws + (24 << 20));
  bf16* vtb  = (bf16*)(ws + (32 << 20));
  bf16* ctxb = (bf16*)(ws + (40 << 20));

  cvt_all<<<(2 << 20) / 256, 256, 0, stream>>>(x, Wq, Wk, Wv, Wo,
                                               xb, wqb, wkb, wvb, wob);

  gemm_qkv<<<512, 512, 0, stream>>>(xb, wqb, wkb, wvb, bq, bk, bv,
                                    qbuf, kbuf, vtb, outK, outV);

  attn_fwd<<<1024, 256, 0, stream>>>(qbuf, kbuf, vtb, ctxb);

  gemm_o<<<dim3(MM / 64, DD / 128), 256, 0, stream>>>(ctxb, wob, bo, out);
}

// Round 10
// 188.972 us; speedup vs baseline: 1.0805x; 1.0011x over previous
//
#include <hip/hip_runtime.h>

#define BB 2
#define TT 2048
#define DD 1024
#define HH 16
#define HD 64
#define MM (BB*TT)

typedef __bf16 bf16;
typedef __bf16 bf16x4 __attribute__((ext_vector_type(4)));
typedef __bf16 bf16x8 __attribute__((ext_vector_type(8)));
typedef float  f32x4  __attribute__((ext_vector_type(4)));

#define QSCALE 0.1803368801111244f   // 0.125 * log2(e)
#define M0 16.0f                     // fixed softmax shift (exp2 domain)

__device__ __forceinline__ void gl_lds16(const void* g, void* l) {
  __builtin_amdgcn_global_load_lds(
      (const __attribute__((address_space(1))) void*)g,
      (__attribute__((address_space(3))) void*)l, 16, 0, 0);
}
__device__ __forceinline__ f32x4 mfma16(bf16x8 a, bf16x8 b, f32x4 c) {
  return __builtin_amdgcn_mfma_f32_16x16x32_bf16(a, b, c, 0, 0, 0);
}

// ---------------------------------------------------------------------------
// single fused convert: x (4M elems) + 4 weights (1M each) fp32 -> bf16
// ---------------------------------------------------------------------------
__global__ void cvt_all(const float* __restrict__ x,
                        const float* __restrict__ w0, const float* __restrict__ w1,
                        const float* __restrict__ w2, const float* __restrict__ w3,
                        bf16* __restrict__ xd,
                        bf16* __restrict__ d0, bf16* __restrict__ d1,
                        bf16* __restrict__ d2, bf16* __restrict__ d3) {
  int i = blockIdx.x * blockDim.x + threadIdx.x;   // 2M float4 slots
  const float* s;
  bf16* d;
  int off;
  if (i < (1 << 20)) { s = x; d = xd; off = i; }
  else {
    int j = (i - (1 << 20)) >> 18;
    off = (i - (1 << 20)) & ((1 << 18) - 1);
    s = (j == 0) ? w0 : (j == 1) ? w1 : (j == 2) ? w2 : w3;
    d = (j == 0) ? d0 : (j == 1) ? d1 : (j == 2) ? d2 : d3;
  }
  float4 v = ((const float4*)s)[off];
  bf16x4 o = { (bf16)v.x, (bf16)v.y, (bf16)v.z, (bf16)v.w };
  ((bf16x4*)d)[off] = o;
}

// ---------------------------------------------------------------------------
// Fused QKV, 512 blocks x 512 threads (8 waves, wave grid 4x2).
// R9: FROZEN at R3 (182.2us best). Six structural variants measured and all
// regressed: BK64-restructure (R2, +56MB epilogue traffic), HIP dbuf (R4,
// M0 serialization), BK64-samegrid (R5, +drain exposure), 4-blocks/CU (R6,
// +60% staging redundancy), counted-vmcnt (R7, over-constrained scheduler),
// V-path K-rotation (R8, +20MB FETCH: broke QK/V L2 panel sharing).
// This 2-barrier BK=32 compiler-scheduled loop IS the structure optimum
// (~645 TF = the known 2-phase ceiling). Swizzle: LDS[r][c]=G[r][c^((r>>1)&3)]
// via pre-swizzled source; read XORs back -> 0 bank conflicts.
// Co-resident pair per CU = QK(g) + V(g): same X panel slices in lockstep
// -> L2 sharing (do NOT de-phase; R8 lesson).
// ---------------------------------------------------------------------------
__launch_bounds__(512)
__global__ void gemm_qkv(const bf16* __restrict__ X,
                         const bf16* __restrict__ Wq, const bf16* __restrict__ Wk,
                         const bf16* __restrict__ Wv,
                         const float* __restrict__ bq, const float* __restrict__ bk,
                         const float* __restrict__ bv,
                         bf16* __restrict__ qb, bf16* __restrict__ kb,
                         bf16* __restrict__ vtb,
                         float* __restrict__ kf, float* __restrict__ vf) {
  __shared__ bf16 sA[128 * 32];      // 8 KB
  __shared__ bf16 sB[2][128 * 32];   // 16 KB
  const int tid  = threadIdx.x;
  const int wv   = tid >> 6;
  const int lane = tid & 63;
  const int quad = lane >> 4, l15 = lane & 15;
  const int wy   = wv >> 1, wx = wv & 1;      // wy 0..3, wx 0..1
  const int g    = blockIdx.x >> 4;
  const int j    = blockIdx.x & 15;
  const int row  = tid >> 2;                  // 0..127
  const int c8   = ((tid & 3) ^ ((row >> 1) & 3)) * 8;  // swizzled source chunk
  const int rsw  = (l15 >> 1) & 3;            // read-side XOR
  char* lA  = (char*)sA    + wv * 1024;
  char* lB0 = (char*)sB[0] + wv * 1024;
  char* lB1 = (char*)sB[1] + wv * 1024;

  if (j < 8) {
    const int m0 = g * 128;                   // tokens
    const int n0 = j * 128;                   // output dim
    const bf16* Ab  = X  + (size_t)(m0 + row) * DD + c8;
    const bf16* Bqb = Wq + (size_t)(n0 + row) * DD + c8;
    const bf16* Bkb = Wk + (size_t)(n0 + row) * DD + c8;
    f32x4 accq[2][4] = {}, acck[2][4] = {};
    for (int k0 = 0; k0 < DD; k0 += 32) {
      gl_lds16(Ab  + k0, lA);
      gl_lds16(Bqb + k0, lB0);
      gl_lds16(Bkb + k0, lB1);
      __syncthreads();
      bf16x8 af[2], bq_[4], bk_[4];
#pragma unroll
      for (int mi = 0; mi < 2; mi++)
        af[mi] = *(const bf16x8*)(sA + (wy * 32 + mi * 16 + l15) * 32
                                     + ((quad ^ rsw) * 8));
#pragma unroll
      for (int ni = 0; ni < 4; ni++) {
        bq_[ni] = *(const bf16x8*)(sB[0] + (wx * 64 + ni * 16 + l15) * 32
                                         + ((quad ^ rsw) * 8));
        bk_[ni] = *(const bf16x8*)(sB[1] + (wx * 64 + ni * 16 + l15) * 32
                                         + ((quad ^ rsw) * 8));
      }
#pragma unroll
      for (int mi = 0; mi < 2; mi++)
#pragma unroll
        for (int ni = 0; ni < 4; ni++) {
          accq[mi][ni] = mfma16(af[mi], bq_[ni], accq[mi][ni]);
          acck[mi][ni] = mfma16(af[mi], bk_[ni], acck[mi][ni]);
        }
      __syncthreads();
    }
    for (int mi = 0; mi < 2; mi++)
      for (int ni = 0; ni < 4; ni++)
        for (int r = 0; r < 4; r++) {
          int m = m0 + wy * 32 + mi * 16 + quad * 4 + r;
          int n = n0 + wx * 64 + ni * 16 + l15;
          int b = m >> 11, t = m & (TT - 1);
          int h = n >> 6,  d = n & (HD - 1);
          size_t idx = ((size_t)(b * HH + h) * TT + t) * HD + d;
          qb[idx] = (bf16)((accq[mi][ni][r] + bq[n]) * QSCALE);
          float vk = acck[mi][ni][r] + bk[n];
          kb[idx] = (bf16)vk;
          kf[idx] = vk;
        }
  } else {
    const int m0 = (j - 8) * 128;             // Wv rows (h*64+d)
    const int n0 = g * 128;                   // tokens
    const bf16* Ab = Wv + (size_t)(m0 + row) * DD + c8;
    const bf16* Bb = X  + (size_t)(n0 + row) * DD + c8;
    f32x4 acc[2][4] = {};
    for (int k0 = 0; k0 < DD; k0 += 32) {
      gl_lds16(Ab + k0, lA);
      gl_lds16(Bb + k0, lB0);
      __syncthreads();
      bf16x8 af[2], bx_[4];
#pragma unroll
      for (int mi = 0; mi < 2; mi++)
        af[mi] = *(const bf16x8*)(sA + (wy * 32 + mi * 16 + l15) * 32
                                     + ((quad ^ rsw) * 8));
#pragma unroll
      for (int ni = 0; ni < 4; ni++)
        bx_[ni] = *(const bf16x8*)(sB[0] + (wx * 64 + ni * 16 + l15) * 32
                                        + ((quad ^ rsw) * 8));
#pragma unroll
      for (int mi = 0; mi < 2; mi++)
#pragma unroll
        for (int ni = 0; ni < 4; ni++)
          acc[mi][ni] = mfma16(af[mi], bx_[ni], acc[mi][ni]);
      __syncthreads();
    }
    for (int mi = 0; mi < 2; mi++) {
      int mbase = m0 + wy * 32 + mi * 16 + quad * 4;
      float brv[4];
      for (int r = 0; r < 4; r++) brv[r] = bv[mbase + r];
      int h = mbase >> 6, dbase = mbase & (HD - 1);
      for (int ni = 0; ni < 4; ni++) {
        int tok = n0 + wx * 64 + ni * 16 + l15;
        int b = tok >> 11, t = tok & (TT - 1);
        int bh = b * HH + h;
        float4 vv;
        float* vp = &vv.x;
        for (int r = 0; r < 4; r++) {
          float v = acc[mi][ni][r] + brv[r];
          vp[r] = v;
          vtb[((size_t)bh * HD + dbase + r) * TT + t] = (bf16)v;
        }
        *(float4*)&vf[((size_t)bh * TT + t) * HD + dbase] = vv;
      }
    }
  }
}

// ---------------------------------------------------------------------------
// gemm_o tile core (BK=64, swizzled) — R3 version (single-buffer, 2 barriers).
// ---------------------------------------------------------------------------
template<int BM, int BN>
__device__ __forceinline__ void tile_core64(const bf16* __restrict__ A,
                                            const bf16* __restrict__ W,
                                            int m0, int n0,
                                            bf16* sA, bf16* sB,
                                            f32x4 (&acc)[BM/32][BN/32]) {
  const int tid  = threadIdx.x;
  const int wv   = tid >> 6;
  const int l15  = tid & 15;
  const int quad = (tid & 63) >> 4;
  const int wy   = wv >> 1, wx = wv & 1;
  const int MI_  = BM / 32, NI_ = BN / 32;
  const int srow = tid >> 3;
  const int schk = (tid & 7) ^ (srow & 7);
  const int rswz = l15 & 7;
  const bf16* Ab = A + (size_t)(m0 + srow) * DD + schk * 8;
  const bf16* Wb = W + (size_t)(n0 + srow) * DD + schk * 8;
  char* lA = (char*)sA + wv * 1024;
  char* lB = (char*)sB + wv * 1024;
  for (int k0 = 0; k0 < DD; k0 += 64) {
#pragma unroll
    for (int j = 0; j < BM / 32; j++)
      gl_lds16(Ab + (size_t)j * 32 * DD + k0, lA + j * 4096);
#pragma unroll
    for (int j = 0; j < BN / 32; j++)
      gl_lds16(Wb + (size_t)j * 32 * DD + k0, lB + j * 4096);
    __syncthreads();
#pragma unroll
    for (int h = 0; h < 2; h++) {
      bf16x8 af[MI_], bw[NI_];
#pragma unroll
      for (int mi = 0; mi < MI_; mi++)
        af[mi] = *(const bf16x8*)(sA + (wy * (BM / 2) + mi * 16 + l15) * 64
                                     + (((h * 4 + quad) ^ rswz) * 8));
#pragma unroll
      for (int ni = 0; ni < NI_; ni++)
        bw[ni] = *(const bf16x8*)(sB + (wx * (BN / 2) + ni * 16 + l15) * 64
                                     + (((h * 4 + quad) ^ rswz) * 8));
#pragma unroll
      for (int mi = 0; mi < MI_; mi++)
#pragma unroll
        for (int ni = 0; ni < NI_; ni++)
          acc[mi][ni] = mfma16(af[mi], bw[ni], acc[mi][ni]);
    }
    __syncthreads();
  }
}

__launch_bounds__(256)
__global__ void gemm_o(const bf16* __restrict__ A, const bf16* __restrict__ W,
                       const float* __restrict__ bias, float* __restrict__ out) {
  __shared__ bf16 sA[64 * 64];
  __shared__ bf16 sB[128 * 64];
  const int m0 = blockIdx.x * 64;
  const int n0 = blockIdx.y * 128;
  f32x4 acc[2][4] = {};
  tile_core64<64, 128>(A, W, m0, n0, sA, sB, acc);
  const int wv = threadIdx.x >> 6;
  const int l15 = threadIdx.x & 15, quad = (threadIdx.x & 63) >> 4;
  const int wy = wv >> 1, wx = wv & 1;
  for (int mi = 0; mi < 2; mi++)
    for (int ni = 0; ni < 4; ni++)
      for (int r = 0; r < 4; r++) {
        int m = m0 + wy * 32 + mi * 16 + quad * 4 + r;
        int n = n0 + wx * 64 + ni * 16 + l15;
        out[(size_t)m * DD + n] = acc[mi][ni][r] + bias[n];
      }
}

// ---------------------------------------------------------------------------
// Flash attention — R9: CU load-balance remap. Grid 1024 = 4 blocks/CU, all
// resident in one shot (no backfill). Work/block = c+1 tiles (causal), c in
// [0,32). Old map put equal c on 32 consecutive bx -> a CU's 4 stride-256
// slots summed 52..80 tiles (~20% tail). New map: v = sl>>2 remapped so the
// 4 stride-8 cosets of v carry c = {w, 31-w, 8+w, 23-w} (sum 62 each) ->
// every CU's resident set sums ~66 tiles. Bijective; loop body unchanged.
// ---------------------------------------------------------------------------
__launch_bounds__(256, 4)
__global__ void attn_fwd(const bf16* __restrict__ Q, const bf16* __restrict__ Kg,
                         const bf16* __restrict__ Vt, bf16* __restrict__ ctx) {
  __shared__ __align__(16) bf16 kbuf[2][4096];
  __shared__ __align__(16) bf16 vbuf[2][4096];
  __shared__ __align__(16) bf16 pbuf[4][1024];
  const int tid  = threadIdx.x;
  const int lane = tid & 63, wv = tid >> 6;
  const int quad = lane >> 4, l15 = lane & 15;
  const int bx = blockIdx.x;
  const int sl = bx >> 3;
  const int v  = sl >> 2;                     // 0..31
  const int w  = v & 7, s2 = v >> 3;
  const int c  = (s2 == 0) ? w : (s2 == 1) ? 31 - w : (s2 == 2) ? 8 + w : 23 - w;
  const int bh = (bx & 7) + 8 * (sl & 3);
  const int qr = c * 64 + wv * 16;
  const int ntiles = c + 1;

  const bf16* Kbh = Kg + (size_t)bh * TT * HD;
  const bf16* Vbh = Vt + (size_t)bh * HD * TT;

  const int k0s = tid >> 3,  c0s = (tid & 7) ^ (k0s & 7);
  const int s1  = 256 + tid;
  const int k1s = s1 >> 3,   c1s = (s1 & 7) ^ (k1s & 7);

  int foff[4][2];
  for (int sub = 0; sub < 4; sub++)
    for (int h = 0; h < 2; h++)
      foff[sub][h] = (((sub * 16 + l15) * 8) + ((h * 4 + quad) ^ (l15 & 7))) * 8;

  const bf16* qp = Q + ((size_t)bh * TT + qr + l15) * HD + quad * 8;
  bf16x8 aq0 = *(const bf16x8*)qp;
  bf16x8 aq1 = *(const bf16x8*)(qp + 32);

  float lrow = 0.f;
  f32x4 acc[4] = {};
  bf16* pb = pbuf[wv];
  const int pswz = l15 & 7;

  gl_lds16(Kbh + (size_t)k0s * HD + c0s * 8, (char*)kbuf[0] + wv * 1024);
  gl_lds16(Kbh + (size_t)k1s * HD + c1s * 8, (char*)kbuf[0] + 4096 + wv * 1024);
  gl_lds16(Vbh + (size_t)k0s * TT + c0s * 8, (char*)vbuf[0] + wv * 1024);
  gl_lds16(Vbh + (size_t)k1s * TT + c1s * 8, (char*)vbuf[0] + 4096 + wv * 1024);

  for (int t = 0; t < ntiles; t++) {
    const int kt = t * 64;
    __syncthreads();
    if (t + 1 < ntiles) {
      bf16* kn = kbuf[(t + 1) & 1];
      bf16* vn = vbuf[(t + 1) & 1];
      gl_lds16(Kbh + (size_t)(kt + 64 + k0s) * HD + c0s * 8, (char*)kn + wv * 1024);
      gl_lds16(Kbh + (size_t)(kt + 64 + k1s) * HD + c1s * 8, (char*)kn + 4096 + wv * 1024);
      gl_lds16(Vbh + (size_t)k0s * TT + kt + 64 + c0s * 8, (char*)vn + wv * 1024);
      gl_lds16(Vbh + (size_t)k1s * TT + kt + 64 + c1s * 8, (char*)vn + 4096 + wv * 1024);
    }
    const bf16* kc = kbuf[t & 1];
    const bf16* vc = vbuf[t & 1];
    const bool last = (t == ntiles - 1);

    float p[4][4];
    for (int sub = 0; sub < 4; sub++) {
      if (last && kt + sub * 16 > qr + 15) {
        p[sub][0] = p[sub][1] = p[sub][2] = p[sub][3] = 0.f;
        continue;
      }
      bf16x8 ak0 = *(const bf16x8*)(kc + foff[sub][0]);
      bf16x8 ak1 = *(const bf16x8*)(kc + foff[sub][1]);
      f32x4 z = {};
      f32x4 st = mfma16(ak0, aq0, z);
      st = mfma16(ak1, aq1, st);
      if (last) {
        for (int r = 0; r < 4; r++) {
          int k_abs = kt + sub * 16 + quad * 4 + r;
          p[sub][r] = (k_abs > qr + l15) ? 0.f
                      : __builtin_amdgcn_exp2f(st[r] - M0);
        }
      } else {
        for (int r = 0; r < 4; r++)
          p[sub][r] = __builtin_amdgcn_exp2f(st[r] - M0);
      }
      lrow += (p[sub][0] + p[sub][1]) + (p[sub][2] + p[sub][3]);
    }

    for (int sub = 0; sub < 4; sub++) {
      bf16x4 pk = { (bf16)p[sub][0], (bf16)p[sub][1], (bf16)p[sub][2], (bf16)p[sub][3] };
      int cch = sub * 2 + (quad >> 1);
      *(bf16x4*)&pb[l15 * 64 + ((cch ^ pswz) * 8 + (quad & 1) * 4)] = pk;
    }
    bf16x8 ap0 = *(const bf16x8*)&pb[l15 * 64 + ((quad ^ pswz) * 8)];
    bf16x8 ap1 = *(const bf16x8*)&pb[l15 * 64 + (((4 + quad) ^ pswz) * 8)];

    for (int ni = 0; ni < 4; ni++) {
      bf16x8 v0 = *(const bf16x8*)(vc + foff[ni][0]);
      bf16x8 v1 = *(const bf16x8*)(vc + foff[ni][1]);
      acc[ni] = mfma16(ap0, v0, acc[ni]);
      acc[ni] = mfma16(ap1, v1, acc[ni]);
    }
  }

  lrow += __shfl_xor(lrow, 16, 64);
  lrow += __shfl_xor(lrow, 32, 64);
  float invl = 1.f / lrow;
  float invq[4];
  for (int r = 0; r < 4; r++)
    invq[r] = __shfl(invl, (lane & 48) | (quad * 4 + r), 64);
  int b = bh >> 4, h = bh & (HH - 1);
  for (int ni = 0; ni < 4; ni++)
    for (int r = 0; r < 4; r++) {
      int tq = qr + quad * 4 + r;
      ctx[((size_t)(b * TT + tq)) * DD + h * HD + ni * 16 + l15] = (bf16)(acc[ni][r] * invq[r]);
    }
}

// ---------------------------------------------------------------------------
// launch
// ---------------------------------------------------------------------------
extern "C" void kernel_launch(void* const* d_in, const int* in_sizes, int n_in,
                              void* d_out, int out_size, void* d_ws, size_t ws_size,
                              hipStream_t stream) {
  const float* x  = (const float*)d_in[0];
  const float* Wq = (const float*)d_in[1];
  const float* bq = (const float*)d_in[2];
  const float* Wk = (const float*)d_in[3];
  const float* bk = (const float*)d_in[4];
  const float* Wv = (const float*)d_in[5];
  const float* bv = (const float*)d_in[6];
  const float* Wo = (const float*)d_in[7];
  const float* bo = (const float*)d_in[8];
  float* out = (float*)d_out;
  float* outK = out + (size_t)MM * DD;
  float* outV = out + (size_t)2 * MM * DD;

  char* ws = (char*)d_ws;
  bf16* xb   = (bf16*)(ws);
  bf16* wqb  = (bf16*)(ws + (8  << 20));
  bf16* wkb  = (bf16*)(ws + (10 << 20));
  bf16* wvb  = (bf16*)(ws + (12 << 20));
  bf16* wob  = (bf16*)(ws + (14 << 20));
  bf16* qbuf = (bf16*)(ws + (16 << 20));
  bf16* kbuf = (bf16*)(ws + (24 << 20));
  bf16* vtb  = (bf16*)(ws + (32 << 20));
  bf16* ctxb = (bf16*)(ws + (40 << 20));

  cvt_all<<<(2 << 20) / 256, 256, 0, stream>>>(x, Wq, Wk, Wv, Wo,
                                               xb, wqb, wkb, wvb, wob);

  gemm_qkv<<<512, 512, 0, stream>>>(xb, wqb, wkb, wvb, bq, bk, bv,
                                    qbuf, kbuf, vtb, outK, outV);

  attn_fwd<<<1024, 256, 0, stream>>>(qbuf, kbuf, vtb, ctxb);

  gemm_o<<<dim3(MM / 64, DD / 128), 256, 0, stream>>>(ctxb, wob, bo, out);
}

// Round 11
// 185.791 us; speedup vs baseline: 1.0990x; 1.0171x over previous
//
#include <hip/hip_runtime.h>

#define BB 2
#define TT 2048
#define DD 1024
#define HH 16
#define HD 64
#define MM (BB*TT)

typedef __bf16 bf16;
typedef __bf16 bf16x4 __attribute__((ext_vector_type(4)));
typedef __bf16 bf16x8 __attribute__((ext_vector_type(8)));
typedef float  f32x4  __attribute__((ext_vector_type(4)));

#define QSCALE 0.1803368801111244f   // 0.125 * log2(e)
#define M0 16.0f                     // fixed softmax shift (exp2 domain)

__device__ __forceinline__ void gl_lds16(const void* g, void* l) {
  __builtin_amdgcn_global_load_lds(
      (const __attribute__((address_space(1))) void*)g,
      (__attribute__((address_space(3))) void*)l, 16, 0, 0);
}
__device__ __forceinline__ f32x4 mfma16(bf16x8 a, bf16x8 b, f32x4 c) {
  return __builtin_amdgcn_mfma_f32_16x16x32_bf16(a, b, c, 0, 0, 0);
}

// ---------------------------------------------------------------------------
// single fused convert: x (4M elems) + 4 weights (1M each) fp32 -> bf16
// ---------------------------------------------------------------------------
__global__ void cvt_all(const float* __restrict__ x,
                        const float* __restrict__ w0, const float* __restrict__ w1,
                        const float* __restrict__ w2, const float* __restrict__ w3,
                        bf16* __restrict__ xd,
                        bf16* __restrict__ d0, bf16* __restrict__ d1,
                        bf16* __restrict__ d2, bf16* __restrict__ d3) {
  int i = blockIdx.x * blockDim.x + threadIdx.x;   // 2M float4 slots
  const float* s;
  bf16* d;
  int off;
  if (i < (1 << 20)) { s = x; d = xd; off = i; }
  else {
    int j = (i - (1 << 20)) >> 18;
    off = (i - (1 << 20)) & ((1 << 18) - 1);
    s = (j == 0) ? w0 : (j == 1) ? w1 : (j == 2) ? w2 : w3;
    d = (j == 0) ? d0 : (j == 1) ? d1 : (j == 2) ? d2 : d3;
  }
  float4 v = ((const float4*)s)[off];
  bf16x4 o = { (bf16)v.x, (bf16)v.y, (bf16)v.z, (bf16)v.w };
  ((bf16x4*)d)[off] = o;
}

// ---------------------------------------------------------------------------
// Fused QKV, 512 blocks x 512 threads (8 waves, wave grid 4x2).
// FROZEN at R3 (182.2us best). Seven structural variants measured, all
// regressed: BK64-restructure (R2), HIP dbuf (R4), BK64-samegrid (R5),
// 4-blocks/CU (R6), counted-vmcnt (R7), V K-rotation (R8, broke QK/V L2
// sharing), attn c-remap (R9, broke linear-map same-head residency).
// This 2-barrier BK=32 compiler-scheduled loop IS the structure optimum.
// Swizzle: LDS[r][c]=G[r][c^((r>>1)&3)] via pre-swizzled source -> 0 bank
// conflicts. Co-resident pair per CU = QK(g)+V(g): same X panel in lockstep.
// ---------------------------------------------------------------------------
__launch_bounds__(512)
__global__ void gemm_qkv(const bf16* __restrict__ X,
                         const bf16* __restrict__ Wq, const bf16* __restrict__ Wk,
                         const bf16* __restrict__ Wv,
                         const float* __restrict__ bq, const float* __restrict__ bk,
                         const float* __restrict__ bv,
                         bf16* __restrict__ qb, bf16* __restrict__ kb,
                         bf16* __restrict__ vtb,
                         float* __restrict__ kf, float* __restrict__ vf) {
  __shared__ bf16 sA[128 * 32];      // 8 KB
  __shared__ bf16 sB[2][128 * 32];   // 16 KB
  const int tid  = threadIdx.x;
  const int wv   = tid >> 6;
  const int lane = tid & 63;
  const int quad = lane >> 4, l15 = lane & 15;
  const int wy   = wv >> 1, wx = wv & 1;      // wy 0..3, wx 0..1
  const int g    = blockIdx.x >> 4;
  const int j    = blockIdx.x & 15;
  const int row  = tid >> 2;                  // 0..127
  const int c8   = ((tid & 3) ^ ((row >> 1) & 3)) * 8;  // swizzled source chunk
  const int rsw  = (l15 >> 1) & 3;            // read-side XOR
  char* lA  = (char*)sA    + wv * 1024;
  char* lB0 = (char*)sB[0] + wv * 1024;
  char* lB1 = (char*)sB[1] + wv * 1024;

  if (j < 8) {
    const int m0 = g * 128;                   // tokens
    const int n0 = j * 128;                   // output dim
    const bf16* Ab  = X  + (size_t)(m0 + row) * DD + c8;
    const bf16* Bqb = Wq + (size_t)(n0 + row) * DD + c8;
    const bf16* Bkb = Wk + (size_t)(n0 + row) * DD + c8;
    f32x4 accq[2][4] = {}, acck[2][4] = {};
    for (int k0 = 0; k0 < DD; k0 += 32) {
      gl_lds16(Ab  + k0, lA);
      gl_lds16(Bqb + k0, lB0);
      gl_lds16(Bkb + k0, lB1);
      __syncthreads();
      bf16x8 af[2], bq_[4], bk_[4];
#pragma unroll
      for (int mi = 0; mi < 2; mi++)
        af[mi] = *(const bf16x8*)(sA + (wy * 32 + mi * 16 + l15) * 32
                                     + ((quad ^ rsw) * 8));
#pragma unroll
      for (int ni = 0; ni < 4; ni++) {
        bq_[ni] = *(const bf16x8*)(sB[0] + (wx * 64 + ni * 16 + l15) * 32
                                         + ((quad ^ rsw) * 8));
        bk_[ni] = *(const bf16x8*)(sB[1] + (wx * 64 + ni * 16 + l15) * 32
                                         + ((quad ^ rsw) * 8));
      }
#pragma unroll
      for (int mi = 0; mi < 2; mi++)
#pragma unroll
        for (int ni = 0; ni < 4; ni++) {
          accq[mi][ni] = mfma16(af[mi], bq_[ni], accq[mi][ni]);
          acck[mi][ni] = mfma16(af[mi], bk_[ni], acck[mi][ni]);
        }
      __syncthreads();
    }
    for (int mi = 0; mi < 2; mi++)
      for (int ni = 0; ni < 4; ni++)
        for (int r = 0; r < 4; r++) {
          int m = m0 + wy * 32 + mi * 16 + quad * 4 + r;
          int n = n0 + wx * 64 + ni * 16 + l15;
          int b = m >> 11, t = m & (TT - 1);
          int h = n >> 6,  d = n & (HD - 1);
          size_t idx = ((size_t)(b * HH + h) * TT + t) * HD + d;
          qb[idx] = (bf16)((accq[mi][ni][r] + bq[n]) * QSCALE);
          float vk = acck[mi][ni][r] + bk[n];
          kb[idx] = (bf16)vk;
          kf[idx] = vk;
        }
  } else {
    const int m0 = (j - 8) * 128;             // Wv rows (h*64+d)
    const int n0 = g * 128;                   // tokens
    const bf16* Ab = Wv + (size_t)(m0 + row) * DD + c8;
    const bf16* Bb = X  + (size_t)(n0 + row) * DD + c8;
    f32x4 acc[2][4] = {};
    for (int k0 = 0; k0 < DD; k0 += 32) {
      gl_lds16(Ab + k0, lA);
      gl_lds16(Bb + k0, lB0);
      __syncthreads();
      bf16x8 af[2], bx_[4];
#pragma unroll
      for (int mi = 0; mi < 2; mi++)
        af[mi] = *(const bf16x8*)(sA + (wy * 32 + mi * 16 + l15) * 32
                                     + ((quad ^ rsw) * 8));
#pragma unroll
      for (int ni = 0; ni < 4; ni++)
        bx_[ni] = *(const bf16x8*)(sB[0] + (wx * 64 + ni * 16 + l15) * 32
                                        + ((quad ^ rsw) * 8));
#pragma unroll
      for (int mi = 0; mi < 2; mi++)
#pragma unroll
        for (int ni = 0; ni < 4; ni++)
          acc[mi][ni] = mfma16(af[mi], bx_[ni], acc[mi][ni]);
      __syncthreads();
    }
    for (int mi = 0; mi < 2; mi++) {
      int mbase = m0 + wy * 32 + mi * 16 + quad * 4;
      float brv[4];
      for (int r = 0; r < 4; r++) brv[r] = bv[mbase + r];
      int h = mbase >> 6, dbase = mbase & (HD - 1);
      for (int ni = 0; ni < 4; ni++) {
        int tok = n0 + wx * 64 + ni * 16 + l15;
        int b = tok >> 11, t = tok & (TT - 1);
        int bh = b * HH + h;
        float4 vv;
        float* vp = &vv.x;
        for (int r = 0; r < 4; r++) {
          float v = acc[mi][ni][r] + brv[r];
          vp[r] = v;
          vtb[((size_t)bh * HD + dbase + r) * TT + t] = (bf16)v;
        }
        *(float4*)&vf[((size_t)bh * TT + t) * HD + dbase] = vv;
      }
    }
  }
}

// ---------------------------------------------------------------------------
// gemm_o tile core (BK=64, swizzled) — R3 version (single-buffer, 2 barriers).
// ---------------------------------------------------------------------------
template<int BM, int BN>
__device__ __forceinline__ void tile_core64(const bf16* __restrict__ A,
                                            const bf16* __restrict__ W,
                                            int m0, int n0,
                                            bf16* sA, bf16* sB,
                                            f32x4 (&acc)[BM/32][BN/32]) {
  const int tid  = threadIdx.x;
  const int wv   = tid >> 6;
  const int l15  = tid & 15;
  const int quad = (tid & 63) >> 4;
  const int wy   = wv >> 1, wx = wv & 1;
  const int MI_  = BM / 32, NI_ = BN / 32;
  const int srow = tid >> 3;
  const int schk = (tid & 7) ^ (srow & 7);
  const int rswz = l15 & 7;
  const bf16* Ab = A + (size_t)(m0 + srow) * DD + schk * 8;
  const bf16* Wb = W + (size_t)(n0 + srow) * DD + schk * 8;
  char* lA = (char*)sA + wv * 1024;
  char* lB = (char*)sB + wv * 1024;
  for (int k0 = 0; k0 < DD; k0 += 64) {
#pragma unroll
    for (int j = 0; j < BM / 32; j++)
      gl_lds16(Ab + (size_t)j * 32 * DD + k0, lA + j * 4096);
#pragma unroll
    for (int j = 0; j < BN / 32; j++)
      gl_lds16(Wb + (size_t)j * 32 * DD + k0, lB + j * 4096);
    __syncthreads();
#pragma unroll
    for (int h = 0; h < 2; h++) {
      bf16x8 af[MI_], bw[NI_];
#pragma unroll
      for (int mi = 0; mi < MI_; mi++)
        af[mi] = *(const bf16x8*)(sA + (wy * (BM / 2) + mi * 16 + l15) * 64
                                     + (((h * 4 + quad) ^ rswz) * 8));
#pragma unroll
      for (int ni = 0; ni < NI_; ni++)
        bw[ni] = *(const bf16x8*)(sB + (wx * (BN / 2) + ni * 16 + l15) * 64
                                     + (((h * 4 + quad) ^ rswz) * 8));
#pragma unroll
      for (int mi = 0; mi < MI_; mi++)
#pragma unroll
        for (int ni = 0; ni < NI_; ni++)
          acc[mi][ni] = mfma16(af[mi], bw[ni], acc[mi][ni]);
    }
    __syncthreads();
  }
}

__launch_bounds__(256)
__global__ void gemm_o(const bf16* __restrict__ A, const bf16* __restrict__ W,
                       const float* __restrict__ bias, float* __restrict__ out) {
  __shared__ bf16 sA[64 * 64];
  __shared__ bf16 sB[128 * 64];
  const int m0 = blockIdx.x * 64;
  const int n0 = blockIdx.y * 128;
  f32x4 acc[2][4] = {};
  tile_core64<64, 128>(A, W, m0, n0, sA, sB, acc);
  const int wv = threadIdx.x >> 6;
  const int l15 = threadIdx.x & 15, quad = (threadIdx.x & 63) >> 4;
  const int wy = wv >> 1, wx = wv & 1;
  for (int mi = 0; mi < 2; mi++)
    for (int ni = 0; ni < 4; ni++)
      for (int r = 0; r < 4; r++) {
        int m = m0 + wy * 32 + mi * 16 + quad * 4 + r;
        int n = n0 + wx * 64 + ni * 16 + l15;
        out[(size_t)m * DD + n] = acc[mi][ni][r] + bias[n];
      }
}

// ---------------------------------------------------------------------------
// Flash attention — R10: R3 mapping restored (R9 remap cost ~2us: linear map
// already gave same-head-per-CU K/V residency). NEW: T5 s_setprio around the
// MFMA clusters (m191: +4-7% on attn when co-resident blocks are at
// different phases — true here: 4 independent blocks/CU). Pure hint.
// ---------------------------------------------------------------------------
__launch_bounds__(256, 4)
__global__ void attn_fwd(const bf16* __restrict__ Q, const bf16* __restrict__ Kg,
                         const bf16* __restrict__ Vt, bf16* __restrict__ ctx) {
  __shared__ __align__(16) bf16 kbuf[2][4096];
  __shared__ __align__(16) bf16 vbuf[2][4096];
  __shared__ __align__(16) bf16 pbuf[4][1024];
  const int tid  = threadIdx.x;
  const int lane = tid & 63, wv = tid >> 6;
  const int quad = lane >> 4, l15 = lane & 15;
  const int bx = blockIdx.x;
  const int sl = bx >> 3;
  const int c  = 31 - (sl >> 2);
  const int bh = (bx & 7) + 8 * (sl & 3);
  const int qr = c * 64 + wv * 16;
  const int ntiles = c + 1;

  const bf16* Kbh = Kg + (size_t)bh * TT * HD;
  const bf16* Vbh = Vt + (size_t)bh * HD * TT;

  const int k0s = tid >> 3,  c0s = (tid & 7) ^ (k0s & 7);
  const int s1  = 256 + tid;
  const int k1s = s1 >> 3,   c1s = (s1 & 7) ^ (k1s & 7);

  int foff[4][2];
  for (int sub = 0; sub < 4; sub++)
    for (int h = 0; h < 2; h++)
      foff[sub][h] = (((sub * 16 + l15) * 8) + ((h * 4 + quad) ^ (l15 & 7))) * 8;

  const bf16* qp = Q + ((size_t)bh * TT + qr + l15) * HD + quad * 8;
  bf16x8 aq0 = *(const bf16x8*)qp;
  bf16x8 aq1 = *(const bf16x8*)(qp + 32);

  float lrow = 0.f;
  f32x4 acc[4] = {};
  bf16* pb = pbuf[wv];
  const int pswz = l15 & 7;

  gl_lds16(Kbh + (size_t)k0s * HD + c0s * 8, (char*)kbuf[0] + wv * 1024);
  gl_lds16(Kbh + (size_t)k1s * HD + c1s * 8, (char*)kbuf[0] + 4096 + wv * 1024);
  gl_lds16(Vbh + (size_t)k0s * TT + c0s * 8, (char*)vbuf[0] + wv * 1024);
  gl_lds16(Vbh + (size_t)k1s * TT + c1s * 8, (char*)vbuf[0] + 4096 + wv * 1024);

  for (int t = 0; t < ntiles; t++) {
    const int kt = t * 64;
    __syncthreads();
    if (t + 1 < ntiles) {
      bf16* kn = kbuf[(t + 1) & 1];
      bf16* vn = vbuf[(t + 1) & 1];
      gl_lds16(Kbh + (size_t)(kt + 64 + k0s) * HD + c0s * 8, (char*)kn + wv * 1024);
      gl_lds16(Kbh + (size_t)(kt + 64 + k1s) * HD + c1s * 8, (char*)kn + 4096 + wv * 1024);
      gl_lds16(Vbh + (size_t)k0s * TT + kt + 64 + c0s * 8, (char*)vn + wv * 1024);
      gl_lds16(Vbh + (size_t)k1s * TT + kt + 64 + c1s * 8, (char*)vn + 4096 + wv * 1024);
    }
    const bf16* kc = kbuf[t & 1];
    const bf16* vc = vbuf[t & 1];
    const bool last = (t == ntiles - 1);

    float p[4][4];
    for (int sub = 0; sub < 4; sub++) {
      if (last && kt + sub * 16 > qr + 15) {
        p[sub][0] = p[sub][1] = p[sub][2] = p[sub][3] = 0.f;
        continue;
      }
      bf16x8 ak0 = *(const bf16x8*)(kc + foff[sub][0]);
      bf16x8 ak1 = *(const bf16x8*)(kc + foff[sub][1]);
      __builtin_amdgcn_s_setprio(1);
      f32x4 z = {};
      f32x4 st = mfma16(ak0, aq0, z);
      st = mfma16(ak1, aq1, st);
      __builtin_amdgcn_s_setprio(0);
      if (last) {
        for (int r = 0; r < 4; r++) {
          int k_abs = kt + sub * 16 + quad * 4 + r;
          p[sub][r] = (k_abs > qr + l15) ? 0.f
                      : __builtin_amdgcn_exp2f(st[r] - M0);
        }
      } else {
        for (int r = 0; r < 4; r++)
          p[sub][r] = __builtin_amdgcn_exp2f(st[r] - M0);
      }
      lrow += (p[sub][0] + p[sub][1]) + (p[sub][2] + p[sub][3]);
    }

    for (int sub = 0; sub < 4; sub++) {
      bf16x4 pk = { (bf16)p[sub][0], (bf16)p[sub][1], (bf16)p[sub][2], (bf16)p[sub][3] };
      int cch = sub * 2 + (quad >> 1);
      *(bf16x4*)&pb[l15 * 64 + ((cch ^ pswz) * 8 + (quad & 1) * 4)] = pk;
    }
    bf16x8 ap0 = *(const bf16x8*)&pb[l15 * 64 + ((quad ^ pswz) * 8)];
    bf16x8 ap1 = *(const bf16x8*)&pb[l15 * 64 + (((4 + quad) ^ pswz) * 8)];

    __builtin_amdgcn_s_setprio(1);
    for (int ni = 0; ni < 4; ni++) {
      bf16x8 v0 = *(const bf16x8*)(vc + foff[ni][0]);
      bf16x8 v1 = *(const bf16x8*)(vc + foff[ni][1]);
      acc[ni] = mfma16(ap0, v0, acc[ni]);
      acc[ni] = mfma16(ap1, v1, acc[ni]);
    }
    __builtin_amdgcn_s_setprio(0);
  }

  lrow += __shfl_xor(lrow, 16, 64);
  lrow += __shfl_xor(lrow, 32, 64);
  float invl = 1.f / lrow;
  float invq[4];
  for (int r = 0; r < 4; r++)
    invq[r] = __shfl(invl, (lane & 48) | (quad * 4 + r), 64);
  int b = bh >> 4, h = bh & (HH - 1);
  for (int ni = 0; ni < 4; ni++)
    for (int r = 0; r < 4; r++) {
      int tq = qr + quad * 4 + r;
      ctx[((size_t)(b * TT + tq)) * DD + h * HD + ni * 16 + l15] = (bf16)(acc[ni][r] * invq[r]);
    }
}

// ---------------------------------------------------------------------------
// launch
// ---------------------------------------------------------------------------
extern "C" void kernel_launch(void* const* d_in, const int* in_sizes, int n_in,
                              void* d_out, int out_size, void* d_ws, size_t ws_size,
                              hipStream_t stream) {
  const float* x  = (const float*)d_in[0];
  const float* Wq = (const float*)d_in[1];
  const float* bq = (const float*)d_in[2];
  const float* Wk = (const float*)d_in[3];
  const float* bk = (const float*)d_in[4];
  const float* Wv = (const float*)d_in[5];
  const float* bv = (const float*)d_in[6];
  const float* Wo = (const float*)d_in[7];
  const float* bo = (const float*)d_in[8];
  float* out = (float*)d_out;
  float* outK = out + (size_t)MM * DD;
  float* outV = out + (size_t)2 * MM * DD;

  char* ws = (char*)d_ws;
  bf16* xb   = (bf16*)(ws);
  bf16* wqb  = (bf16*)(ws + (8  << 20));
  bf16* wkb  = (bf16*)(ws + (10 << 20));
  bf16* wvb  = (bf16*)(ws + (12 << 20));
  bf16* wob  = (bf16*)(ws + (14 << 20));
  bf16* qbuf = (bf16*)(ws + (16 << 20));
  bf16* kbuf = (bf16*)(ws + (24 << 20));
  bf16* vtb  = (bf16*)(ws + (32 << 20));
  bf16* ctxb = (bf16*)(ws + (40 << 20));

  cvt_all<<<(2 << 20) / 256, 256, 0, stream>>>(x, Wq, Wk, Wv, Wo,
                                               xb, wqb, wkb, wvb, wob);

  gemm_qkv<<<512, 512, 0, stream>>>(xb, wqb, wkb, wvb, bq, bk, bv,
                                    qbuf, kbuf, vtb, outK, outV);

  attn_fwd<<<1024, 256, 0, stream>>>(qbuf, kbuf, vtb, ctxb);

  gemm_o<<<dim3(MM / 64, DD / 128), 256, 0, stream>>>(ctxb, wob, bo, out);
}

// Round 12
// 181.228 us; speedup vs baseline: 1.1266x; 1.0252x over previous
//
#include <hip/hip_runtime.h>

#define BB 2
#define TT 2048
#define DD 1024
#define HH 16
#define HD 64
#define MM (BB*TT)

typedef __bf16 bf16;
typedef __bf16 bf16x4 __attribute__((ext_vector_type(4)));
typedef __bf16 bf16x8 __attribute__((ext_vector_type(8)));
typedef float  f32x4  __attribute__((ext_vector_type(4)));

#define QSCALE 0.1803368801111244f   // 0.125 * log2(e)
#define M0 16.0f                     // fixed softmax shift (exp2 domain)

__device__ __forceinline__ void gl_lds16(const void* g, void* l) {
  __builtin_amdgcn_global_load_lds(
      (const __attribute__((address_space(1))) void*)g,
      (__attribute__((address_space(3))) void*)l, 16, 0, 0);
}
__device__ __forceinline__ f32x4 mfma16(bf16x8 a, bf16x8 b, f32x4 c) {
  return __builtin_amdgcn_mfma_f32_16x16x32_bf16(a, b, c, 0, 0, 0);
}

// ---------------------------------------------------------------------------
// single fused convert: x (4M elems) + 4 weights (1M each) fp32 -> bf16
// ---------------------------------------------------------------------------
__global__ void cvt_all(const float* __restrict__ x,
                        const float* __restrict__ w0, const float* __restrict__ w1,
                        const float* __restrict__ w2, const float* __restrict__ w3,
                        bf16* __restrict__ xd,
                        bf16* __restrict__ d0, bf16* __restrict__ d1,
                        bf16* __restrict__ d2, bf16* __restrict__ d3) {
  int i = blockIdx.x * blockDim.x + threadIdx.x;   // 2M float4 slots
  const float* s;
  bf16* d;
  int off;
  if (i < (1 << 20)) { s = x; d = xd; off = i; }
  else {
    int j = (i - (1 << 20)) >> 18;
    off = (i - (1 << 20)) & ((1 << 18) - 1);
    s = (j == 0) ? w0 : (j == 1) ? w1 : (j == 2) ? w2 : w3;
    d = (j == 0) ? d0 : (j == 1) ? d1 : (j == 2) ? d2 : d3;
  }
  float4 v = ((const float4*)s)[off];
  bf16x4 o = { (bf16)v.x, (bf16)v.y, (bf16)v.z, (bf16)v.w };
  ((bf16x4*)d)[off] = o;
}

// ---------------------------------------------------------------------------
// Fused QKV, 512 blocks x 512 threads (8 waves, wave grid 4x2).
// FINAL = R3 config (182.2us session best). Eight variants measured, all
// regressed: BK64-restructure (R2), HIP dbuf (R4), BK64-samegrid (R5),
// 4-blocks/CU (R6), counted-vmcnt (R7), V K-rotation (R8), attn c-remap
// (R9), attn setprio (R10). This 2-barrier BK=32 compiler-scheduled loop is
// the structure optimum (~645 TF = measured 2-phase ceiling, m233/m230).
// Swizzle: LDS[r][c]=G[r][c^((r>>1)&3)] via pre-swizzled source (rule #21)
// -> SQ_LDS_BANK_CONFLICT 4.2M -> 0 (the session's one banked win).
// Co-resident pair per CU = QK(g)+V(g): same X panel in lockstep -> L2
// sharing (R8 proved de-phasing costs +20MB FETCH).
// Epilogues cover full 128B lines per wave (R2 lesson: half-line stores
// cost +26MB WRITE +31MB FETCH write-allocate amplification).
// ---------------------------------------------------------------------------
__launch_bounds__(512)
__global__ void gemm_qkv(const bf16* __restrict__ X,
                         const bf16* __restrict__ Wq, const bf16* __restrict__ Wk,
                         const bf16* __restrict__ Wv,
                         const float* __restrict__ bq, const float* __restrict__ bk,
                         const float* __restrict__ bv,
                         bf16* __restrict__ qb, bf16* __restrict__ kb,
                         bf16* __restrict__ vtb,
                         float* __restrict__ kf, float* __restrict__ vf) {
  __shared__ bf16 sA[128 * 32];      // 8 KB
  __shared__ bf16 sB[2][128 * 32];   // 16 KB
  const int tid  = threadIdx.x;
  const int wv   = tid >> 6;
  const int lane = tid & 63;
  const int quad = lane >> 4, l15 = lane & 15;
  const int wy   = wv >> 1, wx = wv & 1;      // wy 0..3, wx 0..1
  const int g    = blockIdx.x >> 4;
  const int j    = blockIdx.x & 15;
  const int row  = tid >> 2;                  // 0..127
  const int c8   = ((tid & 3) ^ ((row >> 1) & 3)) * 8;  // swizzled source chunk
  const int rsw  = (l15 >> 1) & 3;            // read-side XOR
  char* lA  = (char*)sA    + wv * 1024;
  char* lB0 = (char*)sB[0] + wv * 1024;
  char* lB1 = (char*)sB[1] + wv * 1024;

  if (j < 8) {
    const int m0 = g * 128;                   // tokens
    const int n0 = j * 128;                   // output dim
    const bf16* Ab  = X  + (size_t)(m0 + row) * DD + c8;
    const bf16* Bqb = Wq + (size_t)(n0 + row) * DD + c8;
    const bf16* Bkb = Wk + (size_t)(n0 + row) * DD + c8;
    f32x4 accq[2][4] = {}, acck[2][4] = {};
    for (int k0 = 0; k0 < DD; k0 += 32) {
      gl_lds16(Ab  + k0, lA);
      gl_lds16(Bqb + k0, lB0);
      gl_lds16(Bkb + k0, lB1);
      __syncthreads();
      bf16x8 af[2], bq_[4], bk_[4];
#pragma unroll
      for (int mi = 0; mi < 2; mi++)
        af[mi] = *(const bf16x8*)(sA + (wy * 32 + mi * 16 + l15) * 32
                                     + ((quad ^ rsw) * 8));
#pragma unroll
      for (int ni = 0; ni < 4; ni++) {
        bq_[ni] = *(const bf16x8*)(sB[0] + (wx * 64 + ni * 16 + l15) * 32
                                         + ((quad ^ rsw) * 8));
        bk_[ni] = *(const bf16x8*)(sB[1] + (wx * 64 + ni * 16 + l15) * 32
                                         + ((quad ^ rsw) * 8));
      }
#pragma unroll
      for (int mi = 0; mi < 2; mi++)
#pragma unroll
        for (int ni = 0; ni < 4; ni++) {
          accq[mi][ni] = mfma16(af[mi], bq_[ni], accq[mi][ni]);
          acck[mi][ni] = mfma16(af[mi], bk_[ni], acck[mi][ni]);
        }
      __syncthreads();
    }
    for (int mi = 0; mi < 2; mi++)
      for (int ni = 0; ni < 4; ni++)
        for (int r = 0; r < 4; r++) {
          int m = m0 + wy * 32 + mi * 16 + quad * 4 + r;
          int n = n0 + wx * 64 + ni * 16 + l15;
          int b = m >> 11, t = m & (TT - 1);
          int h = n >> 6,  d = n & (HD - 1);
          size_t idx = ((size_t)(b * HH + h) * TT + t) * HD + d;
          qb[idx] = (bf16)((accq[mi][ni][r] + bq[n]) * QSCALE);
          float vk = acck[mi][ni][r] + bk[n];
          kb[idx] = (bf16)vk;
          kf[idx] = vk;
        }
  } else {
    const int m0 = (j - 8) * 128;             // Wv rows (h*64+d)
    const int n0 = g * 128;                   // tokens
    const bf16* Ab = Wv + (size_t)(m0 + row) * DD + c8;
    const bf16* Bb = X  + (size_t)(n0 + row) * DD + c8;
    f32x4 acc[2][4] = {};
    for (int k0 = 0; k0 < DD; k0 += 32) {
      gl_lds16(Ab + k0, lA);
      gl_lds16(Bb + k0, lB0);
      __syncthreads();
      bf16x8 af[2], bx_[4];
#pragma unroll
      for (int mi = 0; mi < 2; mi++)
        af[mi] = *(const bf16x8*)(sA + (wy * 32 + mi * 16 + l15) * 32
                                     + ((quad ^ rsw) * 8));
#pragma unroll
      for (int ni = 0; ni < 4; ni++)
        bx_[ni] = *(const bf16x8*)(sB[0] + (wx * 64 + ni * 16 + l15) * 32
                                        + ((quad ^ rsw) * 8));
#pragma unroll
      for (int mi = 0; mi < 2; mi++)
#pragma unroll
        for (int ni = 0; ni < 4; ni++)
          acc[mi][ni] = mfma16(af[mi], bx_[ni], acc[mi][ni]);
      __syncthreads();
    }
    for (int mi = 0; mi < 2; mi++) {
      int mbase = m0 + wy * 32 + mi * 16 + quad * 4;
      float brv[4];
      for (int r = 0; r < 4; r++) brv[r] = bv[mbase + r];
      int h = mbase >> 6, dbase = mbase & (HD - 1);
      for (int ni = 0; ni < 4; ni++) {
        int tok = n0 + wx * 64 + ni * 16 + l15;
        int b = tok >> 11, t = tok & (TT - 1);
        int bh = b * HH + h;
        float4 vv;
        float* vp = &vv.x;
        for (int r = 0; r < 4; r++) {
          float v = acc[mi][ni][r] + brv[r];
          vp[r] = v;
          vtb[((size_t)bh * HD + dbase + r) * TT + t] = (bf16)v;
        }
        *(float4*)&vf[((size_t)bh * TT + t) * HD + dbase] = vv;
      }
    }
  }
}

// ---------------------------------------------------------------------------
// gemm_o tile core (BK=64, swizzled) — single-buffer, 2 barriers.
// ---------------------------------------------------------------------------
template<int BM, int BN>
__device__ __forceinline__ void tile_core64(const bf16* __restrict__ A,
                                            const bf16* __restrict__ W,
                                            int m0, int n0,
                                            bf16* sA, bf16* sB,
                                            f32x4 (&acc)[BM/32][BN/32]) {
  const int tid  = threadIdx.x;
  const int wv   = tid >> 6;
  const int l15  = tid & 15;
  const int quad = (tid & 63) >> 4;
  const int wy   = wv >> 1, wx = wv & 1;
  const int MI_  = BM / 32, NI_ = BN / 32;
  const int srow = tid >> 3;
  const int schk = (tid & 7) ^ (srow & 7);
  const int rswz = l15 & 7;
  const bf16* Ab = A + (size_t)(m0 + srow) * DD + schk * 8;
  const bf16* Wb = W + (size_t)(n0 + srow) * DD + schk * 8;
  char* lA = (char*)sA + wv * 1024;
  char* lB = (char*)sB + wv * 1024;
  for (int k0 = 0; k0 < DD; k0 += 64) {
#pragma unroll
    for (int j = 0; j < BM / 32; j++)
      gl_lds16(Ab + (size_t)j * 32 * DD + k0, lA + j * 4096);
#pragma unroll
    for (int j = 0; j < BN / 32; j++)
      gl_lds16(Wb + (size_t)j * 32 * DD + k0, lB + j * 4096);
    __syncthreads();
#pragma unroll
    for (int h = 0; h < 2; h++) {
      bf16x8 af[MI_], bw[NI_];
#pragma unroll
      for (int mi = 0; mi < MI_; mi++)
        af[mi] = *(const bf16x8*)(sA + (wy * (BM / 2) + mi * 16 + l15) * 64
                                     + (((h * 4 + quad) ^ rswz) * 8));
#pragma unroll
      for (int ni = 0; ni < NI_; ni++)
        bw[ni] = *(const bf16x8*)(sB + (wx * (BN / 2) + ni * 16 + l15) * 64
                                     + (((h * 4 + quad) ^ rswz) * 8));
#pragma unroll
      for (int mi = 0; mi < MI_; mi++)
#pragma unroll
        for (int ni = 0; ni < NI_; ni++)
          acc[mi][ni] = mfma16(af[mi], bw[ni], acc[mi][ni]);
    }
    __syncthreads();
  }
}

__launch_bounds__(256)
__global__ void gemm_o(const bf16* __restrict__ A, const bf16* __restrict__ W,
                       const float* __restrict__ bias, float* __restrict__ out) {
  __shared__ bf16 sA[64 * 64];
  __shared__ bf16 sB[128 * 64];
  const int m0 = blockIdx.x * 64;
  const int n0 = blockIdx.y * 128;
  f32x4 acc[2][4] = {};
  tile_core64<64, 128>(A, W, m0, n0, sA, sB, acc);
  const int wv = threadIdx.x >> 6;
  const int l15 = threadIdx.x & 15, quad = (threadIdx.x & 63) >> 4;
  const int wy = wv >> 1, wx = wv & 1;
  for (int mi = 0; mi < 2; mi++)
    for (int ni = 0; ni < 4; ni++)
      for (int r = 0; r < 4; r++) {
        int m = m0 + wy * 32 + mi * 16 + quad * 4 + r;
        int n = n0 + wx * 64 + ni * 16 + l15;
        out[(size_t)m * DD + n] = acc[mi][ni][r] + bias[n];
      }
}

// ---------------------------------------------------------------------------
// Flash attention — R3 config (linear c-map: same-head-per-CU K/V residency;
// R9 remap and R10 setprio both regressed ~1-2us).
// ---------------------------------------------------------------------------
__launch_bounds__(256, 4)
__global__ void attn_fwd(const bf16* __restrict__ Q, const bf16* __restrict__ Kg,
                         const bf16* __restrict__ Vt, bf16* __restrict__ ctx) {
  __shared__ __align__(16) bf16 kbuf[2][4096];
  __shared__ __align__(16) bf16 vbuf[2][4096];
  __shared__ __align__(16) bf16 pbuf[4][1024];
  const int tid  = threadIdx.x;
  const int lane = tid & 63, wv = tid >> 6;
  const int quad = lane >> 4, l15 = lane & 15;
  const int bx = blockIdx.x;
  const int sl = bx >> 3;
  const int c  = 31 - (sl >> 2);
  const int bh = (bx & 7) + 8 * (sl & 3);
  const int qr = c * 64 + wv * 16;
  const int ntiles = c + 1;

  const bf16* Kbh = Kg + (size_t)bh * TT * HD;
  const bf16* Vbh = Vt + (size_t)bh * HD * TT;

  const int k0s = tid >> 3,  c0s = (tid & 7) ^ (k0s & 7);
  const int s1  = 256 + tid;
  const int k1s = s1 >> 3,   c1s = (s1 & 7) ^ (k1s & 7);

  int foff[4][2];
  for (int sub = 0; sub < 4; sub++)
    for (int h = 0; h < 2; h++)
      foff[sub][h] = (((sub * 16 + l15) * 8) + ((h * 4 + quad) ^ (l15 & 7))) * 8;

  const bf16* qp = Q + ((size_t)bh * TT + qr + l15) * HD + quad * 8;
  bf16x8 aq0 = *(const bf16x8*)qp;
  bf16x8 aq1 = *(const bf16x8*)(qp + 32);

  float lrow = 0.f;
  f32x4 acc[4] = {};
  bf16* pb = pbuf[wv];
  const int pswz = l15 & 7;

  gl_lds16(Kbh + (size_t)k0s * HD + c0s * 8, (char*)kbuf[0] + wv * 1024);
  gl_lds16(Kbh + (size_t)k1s * HD + c1s * 8, (char*)kbuf[0] + 4096 + wv * 1024);
  gl_lds16(Vbh + (size_t)k0s * TT + c0s * 8, (char*)vbuf[0] + wv * 1024);
  gl_lds16(Vbh + (size_t)k1s * TT + c1s * 8, (char*)vbuf[0] + 4096 + wv * 1024);

  for (int t = 0; t < ntiles; t++) {
    const int kt = t * 64;
    __syncthreads();
    if (t + 1 < ntiles) {
      bf16* kn = kbuf[(t + 1) & 1];
      bf16* vn = vbuf[(t + 1) & 1];
      gl_lds16(Kbh + (size_t)(kt + 64 + k0s) * HD + c0s * 8, (char*)kn + wv * 1024);
      gl_lds16(Kbh + (size_t)(kt + 64 + k1s) * HD + c1s * 8, (char*)kn + 4096 + wv * 1024);
      gl_lds16(Vbh + (size_t)k0s * TT + kt + 64 + c0s * 8, (char*)vn + wv * 1024);
      gl_lds16(Vbh + (size_t)k1s * TT + kt + 64 + c1s * 8, (char*)vn + 4096 + wv * 1024);
    }
    const bf16* kc = kbuf[t & 1];
    const bf16* vc = vbuf[t & 1];
    const bool last = (t == ntiles - 1);

    float p[4][4];
    for (int sub = 0; sub < 4; sub++) {
      if (last && kt + sub * 16 > qr + 15) {
        p[sub][0] = p[sub][1] = p[sub][2] = p[sub][3] = 0.f;
        continue;
      }
      bf16x8 ak0 = *(const bf16x8*)(kc + foff[sub][0]);
      bf16x8 ak1 = *(const bf16x8*)(kc + foff[sub][1]);
      f32x4 z = {};
      f32x4 st = mfma16(ak0, aq0, z);
      st = mfma16(ak1, aq1, st);
      if (last) {
        for (int r = 0; r < 4; r++) {
          int k_abs = kt + sub * 16 + quad * 4 + r;
          p[sub][r] = (k_abs > qr + l15) ? 0.f
                      : __builtin_amdgcn_exp2f(st[r] - M0);
        }
      } else {
        for (int r = 0; r < 4; r++)
          p[sub][r] = __builtin_amdgcn_exp2f(st[r] - M0);
      }
      lrow += (p[sub][0] + p[sub][1]) + (p[sub][2] + p[sub][3]);
    }

    for (int sub = 0; sub < 4; sub++) {
      bf16x4 pk = { (bf16)p[sub][0], (bf16)p[sub][1], (bf16)p[sub][2], (bf16)p[sub][3] };
      int cch = sub * 2 + (quad >> 1);
      *(bf16x4*)&pb[l15 * 64 + ((cch ^ pswz) * 8 + (quad & 1) * 4)] = pk;
    }
    bf16x8 ap0 = *(const bf16x8*)&pb[l15 * 64 + ((quad ^ pswz) * 8)];
    bf16x8 ap1 = *(const bf16x8*)&pb[l15 * 64 + (((4 + quad) ^ pswz) * 8)];

    for (int ni = 0; ni < 4; ni++) {
      bf16x8 v0 = *(const bf16x8*)(vc + foff[ni][0]);
      bf16x8 v1 = *(const bf16x8*)(vc + foff[ni][1]);
      acc[ni] = mfma16(ap0, v0, acc[ni]);
      acc[ni] = mfma16(ap1, v1, acc[ni]);
    }
  }

  lrow += __shfl_xor(lrow, 16, 64);
  lrow += __shfl_xor(lrow, 32, 64);
  float invl = 1.f / lrow;
  float invq[4];
  for (int r = 0; r < 4; r++)
    invq[r] = __shfl(invl, (lane & 48) | (quad * 4 + r), 64);
  int b = bh >> 4, h = bh & (HH - 1);
  for (int ni = 0; ni < 4; ni++)
    for (int r = 0; r < 4; r++) {
      int tq = qr + quad * 4 + r;
      ctx[((size_t)(b * TT + tq)) * DD + h * HD + ni * 16 + l15] = (bf16)(acc[ni][r] * invq[r]);
    }
}

// ---------------------------------------------------------------------------
// launch
// ---------------------------------------------------------------------------
extern "C" void kernel_launch(void* const* d_in, const int* in_sizes, int n_in,
                              void* d_out, int out_size, void* d_ws, size_t ws_size,
                              hipStream_t stream) {
  const float* x  = (const float*)d_in[0];
  const float* Wq = (const float*)d_in[1];
  const float* bq = (const float*)d_in[2];
  const float* Wk = (const float*)d_in[3];
  const float* bk = (const float*)d_in[4];
  const float* Wv = (const float*)d_in[5];
  const float* bv = (const float*)d_in[6];
  const float* Wo = (const float*)d_in[7];
  const float* bo = (const float*)d_in[8];
  float* out = (float*)d_out;
  float* outK = out + (size_t)MM * DD;
  float* outV = out + (size_t)2 * MM * DD;

  char* ws = (char*)d_ws;
  bf16* xb   = (bf16*)(ws);
  bf16* wqb  = (bf16*)(ws + (8  << 20));
  bf16* wkb  = (bf16*)(ws + (10 << 20));
  bf16* wvb  = (bf16*)(ws + (12 << 20));
  bf16* wob  = (bf16*)(ws + (14 << 20));
  bf16* qbuf = (bf16*)(ws + (16 << 20));
  bf16* kbuf = (bf16*)(ws + (24 << 20));
  bf16* vtb  = (bf16*)(ws + (32 << 20));
  bf16* ctxb = (bf16*)(ws + (40 << 20));

  cvt_all<<<(2 << 20) / 256, 256, 0, stream>>>(x, Wq, Wk, Wv, Wo,
                                               xb, wqb, wkb, wvb, wob);

  gemm_qkv<<<512, 512, 0, stream>>>(xb, wqb, wkb, wvb, bq, bk, bv,
                                    qbuf, kbuf, vtb, outK, outV);

  attn_fwd<<<1024, 256, 0, stream>>>(qbuf, kbuf, vtb, ctxb);

  gemm_o<<<dim3(MM / 64, DD / 128), 256, 0, stream>>>(ctxb, wob, bo, out);
}